// Round 8
// baseline (176.377 us; speedup 1.0000x reference)
//
#include <hip/hip_runtime.h>
#include <hip/hip_bf16.h>
#include <math.h>

#define S_LEN 2048
#define DIM   1024
#define NH    16
#define NL    4
#define NB    2
#define PARTS_PER_BH 80   // sum over 32 q-tiles(64) of ceil((qt+1)/8)
#define ALPHA 0.42466086f // sqrt(0.125 * log2(e)); folded into Q

typedef __attribute__((ext_vector_type(8))) short bf16x8;
typedef __attribute__((ext_vector_type(4))) float f32x4;
typedef unsigned short u16;

__device__ __forceinline__ float bf2f(u16 u) {
  union { unsigned int i; float f; } x; x.i = ((unsigned int)u) << 16; return x.f;
}
__device__ __forceinline__ u16 f2bf(float f) {  // RNE, integer path
  union { float f; unsigned int i; } x; x.f = f;
  unsigned int r = x.i + 0x7fffu + ((x.i >> 16) & 1u);
  return (u16)(r >> 16);
}
__device__ __forceinline__ u16 f2bfq(float f) { // compiler cvt path
  __hip_bfloat16 h = __float2bfloat16(f);
  return *reinterpret_cast<u16*>(&h);
}

__device__ __forceinline__ void g2l16(const void* g, void* l) {
  __builtin_amdgcn_global_load_lds(
      (const __attribute__((address_space(1))) void*)g,
      (__attribute__((address_space(3))) void*)l, 16, 0, 0);
}

// One fused f32->bf16 convert for x, Wq, Wo.
__global__ __launch_bounds__(256)
void cvt_all(const float* __restrict__ x, const float* __restrict__ wq,
             const float* __restrict__ wo, u16* __restrict__ ox,
             u16* __restrict__ owq, u16* __restrict__ owo, int n4x, int n4w) {
  int i = blockIdx.x * blockDim.x + threadIdx.x;
  const float* src; u16* dst; int j;
  if (i < n4x)            { src = x;  dst = ox;  j = i; }
  else if (i < n4x + n4w) { src = wq; dst = owq; j = i - n4x; }
  else                    { src = wo; dst = owo; j = i - n4x - n4w;
                            if (j >= n4w) return; }
  float4 v = ((const float4*)src)[j];
  ushort4 o;
  o.x = f2bf(v.x); o.y = f2bf(v.y); o.z = f2bf(v.z); o.w = f2bf(v.w);
  ((ushort4*)dst)[j] = o;
}

// C = act(A @ Bt^T + bias) * oscale. 128x64 tile, BK=64, 4 waves (2x2).
// 2-phase pipeline: double-buffered LDS, stage(next) issued BEFORE compute(cur),
// ONE barrier per K-step.
template <bool GELU, typename OT>
__global__ __launch_bounds__(256)
void gemm_bt(const u16* __restrict__ A, const u16* __restrict__ Bt,
             const float* __restrict__ bias, OT* __restrict__ C,
             int M, int N, int K, float oscale) {
  __shared__ u16 As[2][128 * 64];
  __shared__ u16 Bs[2][64 * 64];
  const int lane = threadIdx.x & 63, wave = threadIdx.x >> 6;
  const int ln = lane & 15, g = lane >> 4;
  const int m0 = blockIdx.y * 128, n0 = blockIdx.x * 64;
  const int wm = wave >> 1, wn = wave & 1;
  f32x4 acc[4][2] = {};

  auto stage = [&](int buf, int k0) {
#pragma unroll
    for (int rd = 0; rd < 6; ++rd) {
      int ch = rd * 4 + wave;                   // 0..23: 16 A-chunks + 8 B-chunks
      if (ch < 16) {
        int flat = ch * 1024 + lane * 16;
        int row = flat >> 7;
        int within = (flat & 127) ^ ((row & 7) << 4);
        g2l16((const char*)A + ((size_t)(m0 + row) * K + k0) * 2 + within,
              (char*)As[buf] + ch * 1024);
      } else {
        int flat = (ch - 16) * 1024 + lane * 16;
        int row = flat >> 7;
        int within = (flat & 127) ^ ((row & 7) << 4);
        g2l16((const char*)Bt + ((size_t)(n0 + row) * K + k0) * 2 + within,
              (char*)Bs[buf] + (ch - 16) * 1024);
      }
    }
  };

  stage(0, 0);
  __syncthreads();
  const int NT = K / 64;
  for (int t = 0; t < NT; ++t) {
    const int cur = t & 1;
    if (t + 1 < NT) stage(cur ^ 1, (t + 1) * 64);
#pragma unroll
    for (int kc = 0; kc < 2; ++kc) {
      bf16x8 af[4], bfr[2];
#pragma unroll
      for (int i = 0; i < 4; ++i) {
        int ra = wm * 64 + i * 16 + ln;
        af[i] = *(const bf16x8*)((const char*)As[cur] + ra * 128 +
                                 ((kc * 64 + g * 16) ^ ((ra & 7) << 4)));
      }
#pragma unroll
      for (int j = 0; j < 2; ++j) {
        int rb = wn * 32 + j * 16 + ln;
        bfr[j] = *(const bf16x8*)((const char*)Bs[cur] + rb * 128 +
                                  ((kc * 64 + g * 16) ^ ((rb & 7) << 4)));
      }
#pragma unroll
      for (int i = 0; i < 4; ++i)
#pragma unroll
        for (int j = 0; j < 2; ++j)
          acc[i][j] = __builtin_amdgcn_mfma_f32_16x16x32_bf16(af[i], bfr[j], acc[i][j], 0, 0, 0);
    }
    __syncthreads();   // drains this iter's prefetch + fences buffer reuse
  }

#pragma unroll
  for (int j = 0; j < 2; ++j) {
    int gc = n0 + wn * 32 + j * 16 + ln;
    float bv = bias[gc];
#pragma unroll
    for (int i = 0; i < 4; ++i) {
      int gr0 = m0 + wm * 64 + i * 16 + g * 4;
#pragma unroll
      for (int r = 0; r < 4; ++r) {
        float v = acc[i][j][r] + bv;
        if constexpr (GELU) v = 0.5f * v * (1.0f + erff(v * 0.70710678118f));
        v *= oscale;
        if constexpr (sizeof(OT) == 2) C[(size_t)(gr0 + r) * N + gc] = (OT)f2bf(v);
        else                           C[(size_t)(gr0 + r) * N + gc] = (OT)v;
      }
    }
  }
}

// Flash self-attention, token part, K-chunked. QBLK=64 (4 waves x 16 q-rows).
// Swapped QK^T (D[key][q], q=ln lane-local). K fragments read DIRECTLY from
// global (L1/L2-cached; identical across waves) -- no K LDS staging. Only V
// (transposed) and P round-trip through LDS. grid (PARTS_PER_BH, H, B).
__global__ __launch_bounds__(256)
void attn(const u16* __restrict__ Q, const u16* __restrict__ Xb,
          u16* __restrict__ CTXP, float* __restrict__ MP, float* __restrict__ LP) {
  __shared__ u16 Vt[2][64 * 64];
  __shared__ u16 Pw[4][16 * 64];

  const int lane = threadIdx.x & 63, wave = threadIdx.x >> 6;
  const int ln = lane & 15, g = lane >> 4;
  const int h = blockIdx.y, b = blockIdx.z;

  // part -> (qt, chunk); parts(qt) = ceil((qt+1)/8)
  const int p = blockIdx.x;
  int qt, chunk;
  if (p < 8)       { qt = p;                          chunk = 0; }
  else if (p < 24) { int i = p - 8;  qt = 8 + (i >> 1);  chunk = i & 1; }
  else if (p < 48) { int i = p - 24; qt = 16 + i / 3;    chunk = i % 3; }
  else             { int i = p - 48; qt = 24 + (i >> 2); chunk = i & 3; }
  const int kt0 = chunk * 8;
  const int kt1e = kt0 + 8 < qt + 1 ? kt0 + 8 : qt + 1;

  const size_t qrow = (size_t)b * S_LEN + qt * 64 + wave * 16 + ln;
  const bf16x8 qa0 = *(const bf16x8*)(Q + qrow * DIM + h * 64 + g * 8);
  const bf16x8 qa1 = *(const bf16x8*)(Q + qrow * DIM + h * 64 + 32 + g * 8);

  // K fragment base: row (kt*64 + sub*16 + ln) of Q, head h, col g*8
  const u16* Kbase = Q + ((size_t)b * S_LEN) * DIM + h * 64 + g * 8;

  f32x4 acc[4] = {};
  float m_run = -INFINITY;   // per-lane: q = ln (replicated across g)
  float l_run = 0.f;

  const int tid = threadIdx.x;
  const int vr0 = (tid >> 3) * 2;   // key row pair
  const int vc0 = (tid & 7) * 8;    // dim cols
#define VSWZ(c) ((((c) ^ ((c) >> 3)) & 7) << 4)

  // prologue: stage V tile kt0 into buffer 0
  {
    const u16* xsrc = Xb + ((size_t)b * S_LEN + kt0 * 64 + vr0) * DIM + h * 64 + vc0;
    bf16x8 r0 = *(const bf16x8*)xsrc;
    bf16x8 r1 = *(const bf16x8*)(xsrc + DIM);
#pragma unroll
    for (int j = 0; j < 8; ++j) {
      int c = vc0 + j;
      unsigned int pack = (unsigned int)(u16)r0[j] | ((unsigned int)(u16)r1[j] << 16);
      *(unsigned int*)((char*)Vt[0] + c * 128 + ((vr0 * 2) ^ VSWZ(c))) = pack;
    }
  }
  __syncthreads();

  for (int kt = kt0; kt < kt1e; ++kt) {
    const int cur = (kt - kt0) & 1, nxt = cur ^ 1;
    const bool more = (kt + 1 < kt1e);
    bf16x8 nr0, nr1;
    if (more) {
      // prefetch next V tile to regs (issue early; written after the MFMAs)
      const u16* xsrc = Xb + ((size_t)b * S_LEN + (kt + 1) * 64 + vr0) * DIM + h * 64 + vc0;
      nr0 = *(const bf16x8*)xsrc;
      nr1 = *(const bf16x8*)(xsrc + DIM);
    }

    // QK^T SWAPPED: D[key][q]; lane holds key = sub*16 + g*4 + r, q = ln.
    // K fragments straight from global (cache-resident).
    float pv_[4][4];
#pragma unroll
    for (int sub = 0; sub < 4; ++sub) {
      const u16* kp = Kbase + (size_t)(kt * 64 + sub * 16 + ln) * DIM;
      bf16x8 kb0 = *(const bf16x8*)kp;
      bf16x8 kb1 = *(const bf16x8*)(kp + 32);
      f32x4 c = {};
      c = __builtin_amdgcn_mfma_f32_16x16x32_bf16(kb0, qa0, c, 0, 0, 0);
      c = __builtin_amdgcn_mfma_f32_16x16x32_bf16(kb1, qa1, c, 0, 0, 0);
      if (kt == qt) {
#pragma unroll
        for (int r = 0; r < 4; ++r) {
          int key = sub * 16 + g * 4 + r;
          int qi = wave * 16 + ln;
          pv_[sub][r] = (key > qi) ? -INFINITY : c[r];
        }
      } else {
#pragma unroll
        for (int r = 0; r < 4; ++r) pv_[sub][r] = c[r];
      }
    }

    // in-lane row max over this lane's 16 scores, then cross-g butterfly
    float pmax = pv_[0][0];
#pragma unroll
    for (int sub = 0; sub < 4; ++sub)
#pragma unroll
      for (int r = 0; r < 4; ++r) pmax = fmaxf(pmax, pv_[sub][r]);
    pmax = fmaxf(pmax, __shfl_xor(pmax, 16));
    pmax = fmaxf(pmax, __shfl_xor(pmax, 32));

    // defer-rescale (THR=8, log2 domain)
    if (!__all(pmax <= m_run + 8.0f)) {
      float m_new = fmaxf(m_run, pmax);
      float scl = exp2f(m_run - m_new);
      m_run = m_new;
      l_run *= scl;
#pragma unroll
      for (int r = 0; r < 4; ++r) {
        float s = __shfl(scl, g * 4 + r);
#pragma unroll
        for (int ns = 0; ns < 4; ++ns) acc[ns][r] *= s;
      }
    }

    float lsum = 0.f;
#pragma unroll
    for (int sub = 0; sub < 4; ++sub)
#pragma unroll
      for (int r = 0; r < 4; ++r) {
        pv_[sub][r] = exp2f(pv_[sub][r] - m_run);
        lsum += pv_[sub][r];
      }
    lsum += __shfl_xor(lsum, 16);
    lsum += __shfl_xor(lsum, 32);
    l_run += lsum;

    // P store: 4 key-consecutive bf16 per (lane,sub) -> one b64 each
#pragma unroll
    for (int sub = 0; sub < 4; ++sub) {
      uint2 val;
      val.x = (unsigned int)f2bfq(pv_[sub][0]) | ((unsigned int)f2bfq(pv_[sub][1]) << 16);
      val.y = (unsigned int)f2bfq(pv_[sub][2]) | ((unsigned int)f2bfq(pv_[sub][3]) << 16);
      *(uint2*)((char*)Pw[wave] + ln * 128 + ((sub * 32 + g * 8) ^ ((ln & 7) << 4))) = val;
    }

    bf16x8 pa0 = *(const bf16x8*)((const char*)Pw[wave] + ln * 128 + ((g * 16) ^ ((ln & 7) << 4)));
    bf16x8 pa1 = *(const bf16x8*)((const char*)Pw[wave] + ln * 128 + ((64 + g * 16) ^ ((ln & 7) << 4)));
#pragma unroll
    for (int ns = 0; ns < 4; ++ns) {
      int vr = ns * 16 + ln;
      bf16x8 vb0 = *(const bf16x8*)((const char*)Vt[cur] + vr * 128 + ((g * 16) ^ VSWZ(vr)));
      bf16x8 vb1 = *(const bf16x8*)((const char*)Vt[cur] + vr * 128 + ((64 + g * 16) ^ VSWZ(vr)));
      acc[ns] = __builtin_amdgcn_mfma_f32_16x16x32_bf16(pa0, vb0, acc[ns], 0, 0, 0);
      acc[ns] = __builtin_amdgcn_mfma_f32_16x16x32_bf16(pa1, vb1, acc[ns], 0, 0, 0);
    }

    if (more) {
      // write prefetched V^T into next buffer
#pragma unroll
      for (int j = 0; j < 8; ++j) {
        int c = vc0 + j;
        unsigned int pack = (unsigned int)(u16)nr0[j] | ((unsigned int)(u16)nr1[j] << 16);
        *(unsigned int*)((char*)Vt[nxt] + c * 128 + ((vr0 * 2) ^ VSWZ(c))) = pack;
      }
    }
    __syncthreads();
  }

  // write unnormalized bf16 partial ctx + stats (log2-domain m, l)
  const size_t slot = ((size_t)(b * NH + h)) * PARTS_PER_BH + p;
#pragma unroll
  for (int ns = 0; ns < 4; ++ns)
#pragma unroll
    for (int r = 0; r < 4; ++r) {
      int qr = wave * 16 + g * 4 + r;
      CTXP[slot * 4096 + (size_t)qr * 64 + ns * 16 + ln] = f2bfq(acc[ns][r]);
    }
  if (lane < 16) {
    MP[slot * 64 + wave * 16 + lane] = m_run;
    LP[slot * 64 + wave * 16 + lane] = l_run;
  }
}

// Merge K-chunk partials + fold L=4 memory slots (log2 domain), final bf16 ctx.
__global__ __launch_bounds__(256)
void finalize(const u16* __restrict__ Q, const float* __restrict__ PQ,
              const float* __restrict__ PV, const u16* __restrict__ CTXP,
              const float* __restrict__ MP, const float* __restrict__ LP,
              u16* __restrict__ Cout) {
  const int lane = threadIdx.x & 63, wave = threadIdx.x >> 6;
  const size_t row = (size_t)blockIdx.x * 4 + wave;  // (b*H+h)*S + s
  const int s = (int)(row & (S_LEN - 1));
  const int h = (int)((row >> 11) & (NH - 1));
  const int b = (int)(row >> 15);

  const int qt = s >> 6, G = qt >> 3, parts = G + 1;
  const int baseG[4] = {0, 8, 24, 48};
  const int p0 = baseG[G] + (qt & 7) * parts;
  const size_t slot0 = ((size_t)(b * NH + h)) * PARTS_PER_BH + p0;
  const int sr = s & 63;

  float mc[4], lc[4];
  float m_tok = -INFINITY;
#pragma unroll
  for (int c = 0; c < 4; ++c)
    if (c < parts) {
      mc[c] = MP[(slot0 + c) * 64 + sr];
      lc[c] = LP[(slot0 + c) * 64 + sr];
      m_tok = fmaxf(m_tok, mc[c]);
    }
  float l_tok = 0.f, cd = 0.f;
#pragma unroll
  for (int c = 0; c < 4; ++c)
    if (c < parts) {
      float w = exp2f(mc[c] - m_tok);
      l_tok += w * lc[c];
      cd += w * bf2f(CTXP[(slot0 + c) * 4096 + (size_t)sr * 64 + lane]);
    }

  // memory slots (qd carries one ALPHA; multiply by ALPHA for full scale)
  const float qd = bf2f(Q[((size_t)b * S_LEN + s) * DIM + h * 64 + lane]);
  const float* pq = PQ + row * (NL * 64);
  const float* pv = PV + row * (NL * 64);
  float msc[NL];
  float m_fin = m_tok;
#pragma unroll
  for (int lm = 0; lm < NL; ++lm) {
    float prod = qd * pq[lm * 64 + lane];
#pragma unroll
    for (int o = 1; o < 64; o <<= 1) prod += __shfl_xor(prod, o);
    msc[lm] = prod * ALPHA;
    m_fin = fmaxf(m_fin, msc[lm]);
  }
  const float a = exp2f(m_tok - m_fin);
  float l_fin = l_tok * a;
  cd *= a;
#pragma unroll
  for (int lm = 0; lm < NL; ++lm) {
    float w = exp2f(msc[lm] - m_fin);
    l_fin += w;
    cd += w * pv[lm * 64 + lane];
  }
  Cout[((size_t)b * S_LEN + s) * DIM + h * 64 + lane] = f2bf(cd / l_fin);
}

extern "C" void kernel_launch(void* const* d_in, const int* in_sizes, int n_in,
                              void* d_out, int out_size, void* d_ws, size_t ws_size,
                              hipStream_t stream) {
  const float* x  = (const float*)d_in[0];
  const float* pq = (const float*)d_in[1];
  const float* pv = (const float*)d_in[2];
  const float* Wq = (const float*)d_in[3];
  const float* bq = (const float*)d_in[4];
  const float* Wo = (const float*)d_in[5];
  const float* bo = (const float*)d_in[6];
  float* out = (float*)d_out;

  const int M = NB * S_LEN;  // 4096
  u16*   Qws  = (u16*)d_ws;                    // 8 MB (ALPHA-scaled Q, bf16)
  u16*   Cws  = Qws + (size_t)M * DIM;         // 8 MB
  u16*   xbf  = Cws + (size_t)M * DIM;         // 8 MB
  u16*   Wqbf = xbf + (size_t)M * DIM;         // 2 MB
  u16*   Wobf = Wqbf + (size_t)DIM * DIM;      // 2 MB
  u16*   CTXP = Wobf + (size_t)DIM * DIM;      // 2560 slots x 4096 bf16 = 21 MB
  float* MP   = (float*)(CTXP + (size_t)NB * NH * PARTS_PER_BH * 4096);  // 640 KB
  float* LP   = MP + (size_t)NB * NH * PARTS_PER_BH * 64;                // 640 KB

  const int n4x = M * DIM / 4, n4w = DIM * DIM / 4;
  cvt_all<<<(n4x + 2 * n4w + 255) / 256, 256, 0, stream>>>(
      x, Wq, Wo, xbf, Wqbf, Wobf, n4x, n4w);

  gemm_bt<false, u16><<<dim3(DIM / 64, M / 128), 256, 0, stream>>>(
      xbf, Wqbf, bq, Qws, M, DIM, DIM, ALPHA);
  attn<<<dim3(PARTS_PER_BH, NH, NB), 256, 0, stream>>>(Qws, xbf, CTXP, MP, LP);
  finalize<<<NB * NH * S_LEN / 4, 256, 0, stream>>>(Qws, pq, pv, CTXP, MP, LP, Cws);
  gemm_bt<true, float><<<dim3(DIM / 64, M / 128), 256, 0, stream>>>(
      Cws, Wobf, bo, out, M, DIM, DIM, 1.0f);
}

// Round 9
// 140.667 us; speedup vs baseline: 1.2539x; 1.2539x over previous
//
#include <hip/hip_runtime.h>
#include <hip/hip_bf16.h>
#include <math.h>

#define S_LEN 2048
#define DIM   1024
#define NH    16
#define NL    4
#define NB    2
#define PARTS_PER_BH 80   // sum over 32 q-tiles(64) of ceil((qt+1)/8)
#define ALPHA 0.42466086f // sqrt(0.125 * log2(e)); folded into Q

typedef __attribute__((ext_vector_type(8))) short bf16x8;
typedef __attribute__((ext_vector_type(4))) float f32x4;
typedef unsigned short u16;

__device__ __forceinline__ float bf2f(u16 u) {
  union { unsigned int i; float f; } x; x.i = ((unsigned int)u) << 16; return x.f;
}
__device__ __forceinline__ u16 f2bf(float f) {  // RNE, integer path
  union { float f; unsigned int i; } x; x.f = f;
  unsigned int r = x.i + 0x7fffu + ((x.i >> 16) & 1u);
  return (u16)(r >> 16);
}
__device__ __forceinline__ u16 f2bfq(float f) { // compiler cvt path
  __hip_bfloat16 h = __float2bfloat16(f);
  return *reinterpret_cast<u16*>(&h);
}

__device__ __forceinline__ void g2l16(const void* g, void* l) {
  __builtin_amdgcn_global_load_lds(
      (const __attribute__((address_space(1))) void*)g,
      (__attribute__((address_space(3))) void*)l, 16, 0, 0);
}

// gelu via tanh form, tanh via one exp2. |err vs exact erf-gelu| <= ~3e-4.
__device__ __forceinline__ float gelu_fast(float v) {
  float y = 0.79788456f * (v + 0.044715f * v * v * v);
  float e = exp2f(y * 2.88539008f);          // e^(2y)
  float t = 1.0f - 2.0f / (e + 1.0f);        // tanh(y)
  return 0.5f * v * (1.0f + t);
}

// One fused f32->bf16 convert for x, Wq, Wo.
__global__ __launch_bounds__(256)
void cvt_all(const float* __restrict__ x, const float* __restrict__ wq,
             const float* __restrict__ wo, u16* __restrict__ ox,
             u16* __restrict__ owq, u16* __restrict__ owo, int n4x, int n4w) {
  int i = blockIdx.x * blockDim.x + threadIdx.x;
  const float* src; u16* dst; int j;
  if (i < n4x)            { src = x;  dst = ox;  j = i; }
  else if (i < n4x + n4w) { src = wq; dst = owq; j = i - n4x; }
  else                    { src = wo; dst = owo; j = i - n4x - n4w;
                            if (j >= n4w) return; }
  float4 v = ((const float4*)src)[j];
  ushort4 o;
  o.x = f2bf(v.x); o.y = f2bf(v.y); o.z = f2bf(v.z); o.w = f2bf(v.w);
  ((ushort4*)dst)[j] = o;
}

// C = act(A @ Bt^T + bias) * oscale. 128x64 tile, BK=64, 4 waves (2x2).
// 2-phase pipeline + XCD-aware block swizzle (512 blocks, 512%8==0 bijective).
template <bool GELU, typename OT>
__global__ __launch_bounds__(256)
void gemm_bt(const u16* __restrict__ A, const u16* __restrict__ Bt,
             const float* __restrict__ bias, OT* __restrict__ C,
             int M, int N, int K, float oscale) {
  __shared__ u16 As[2][128 * 64];
  __shared__ u16 Bs[2][64 * 64];
  const int lane = threadIdx.x & 63, wave = threadIdx.x >> 6;
  const int ln = lane & 15, g = lane >> 4;
  // XCD swizzle: contiguous chunk of blocks per XCD -> shared A-bands in L2
  const int nwg = gridDim.x * gridDim.y;
  const int flat = blockIdx.y * gridDim.x + blockIdx.x;
  const int swz = (flat & 7) * (nwg >> 3) + (flat >> 3);
  const int m0 = (swz / gridDim.x) * 128, n0 = (swz % gridDim.x) * 64;
  const int wm = wave >> 1, wn = wave & 1;
  f32x4 acc[4][2] = {};

  auto stage = [&](int buf, int k0) {
#pragma unroll
    for (int rd = 0; rd < 6; ++rd) {
      int ch = rd * 4 + wave;                   // 0..23: 16 A-chunks + 8 B-chunks
      if (ch < 16) {
        int flatb = ch * 1024 + lane * 16;
        int row = flatb >> 7;
        int within = (flatb & 127) ^ ((row & 7) << 4);
        g2l16((const char*)A + ((size_t)(m0 + row) * K + k0) * 2 + within,
              (char*)As[buf] + ch * 1024);
      } else {
        int flatb = (ch - 16) * 1024 + lane * 16;
        int row = flatb >> 7;
        int within = (flatb & 127) ^ ((row & 7) << 4);
        g2l16((const char*)Bt + ((size_t)(n0 + row) * K + k0) * 2 + within,
              (char*)Bs[buf] + (ch - 16) * 1024);
      }
    }
  };

  stage(0, 0);
  __syncthreads();
  const int NT = K / 64;
  for (int t = 0; t < NT; ++t) {
    const int cur = t & 1;
    if (t + 1 < NT) stage(cur ^ 1, (t + 1) * 64);
#pragma unroll
    for (int kc = 0; kc < 2; ++kc) {
      bf16x8 af[4], bfr[2];
#pragma unroll
      for (int i = 0; i < 4; ++i) {
        int ra = wm * 64 + i * 16 + ln;
        af[i] = *(const bf16x8*)((const char*)As[cur] + ra * 128 +
                                 ((kc * 64 + g * 16) ^ ((ra & 7) << 4)));
      }
#pragma unroll
      for (int j = 0; j < 2; ++j) {
        int rb = wn * 32 + j * 16 + ln;
        bfr[j] = *(const bf16x8*)((const char*)Bs[cur] + rb * 128 +
                                  ((kc * 64 + g * 16) ^ ((rb & 7) << 4)));
      }
#pragma unroll
      for (int i = 0; i < 4; ++i)
#pragma unroll
        for (int j = 0; j < 2; ++j)
          acc[i][j] = __builtin_amdgcn_mfma_f32_16x16x32_bf16(af[i], bfr[j], acc[i][j], 0, 0, 0);
    }
    __syncthreads();   // drains this iter's prefetch + fences buffer reuse
  }

#pragma unroll
  for (int j = 0; j < 2; ++j) {
    int gc = n0 + wn * 32 + j * 16 + ln;
    float bv = bias[gc];
#pragma unroll
    for (int i = 0; i < 4; ++i) {
      int gr0 = m0 + wm * 64 + i * 16 + g * 4;
#pragma unroll
      for (int r = 0; r < 4; ++r) {
        float v = acc[i][j][r] + bv;
        if constexpr (GELU) v = gelu_fast(v);
        v *= oscale;
        if constexpr (sizeof(OT) == 2) C[(size_t)(gr0 + r) * N + gc] = (OT)f2bf(v);
        else                           C[(size_t)(gr0 + r) * N + gc] = (OT)v;
      }
    }
  }
}

// Flash self-attention, token part, K-chunked. QBLK=64 (4 waves x 16 q-rows).
// Swapped QK^T (D[key][q], q=ln lane-local): in-lane softmax rows, scalar m/l,
// packed b64 P-stores. K staged via global_load_lds (double-buffered); V^T
// staged via regs + swizzled writes. grid (PARTS_PER_BH, H, B). [R6 body]
__global__ __launch_bounds__(256)
void attn(const u16* __restrict__ Q, const u16* __restrict__ Xb,
          u16* __restrict__ CTXP, float* __restrict__ MP, float* __restrict__ LP) {
  __shared__ u16 Ks[2][64 * 64];
  __shared__ u16 Vt[2][64 * 64];
  __shared__ u16 Pw[4][16 * 64];

  const int lane = threadIdx.x & 63, wave = threadIdx.x >> 6;
  const int ln = lane & 15, g = lane >> 4;
  const int h = blockIdx.y, b = blockIdx.z;

  // part -> (qt, chunk); parts(qt) = ceil((qt+1)/8)
  const int p = blockIdx.x;
  int qt, chunk;
  if (p < 8)       { qt = p;                          chunk = 0; }
  else if (p < 24) { int i = p - 8;  qt = 8 + (i >> 1);  chunk = i & 1; }
  else if (p < 48) { int i = p - 24; qt = 16 + i / 3;    chunk = i % 3; }
  else             { int i = p - 48; qt = 24 + (i >> 2); chunk = i & 3; }
  const int kt0 = chunk * 8;
  const int kt1e = kt0 + 8 < qt + 1 ? kt0 + 8 : qt + 1;

  const size_t qrow = (size_t)b * S_LEN + qt * 64 + wave * 16 + ln;
  const bf16x8 qa0 = *(const bf16x8*)(Q + qrow * DIM + h * 64 + g * 8);
  const bf16x8 qa1 = *(const bf16x8*)(Q + qrow * DIM + h * 64 + 32 + g * 8);

  f32x4 acc[4] = {};
  float m_run = -INFINITY;   // per-lane: q = ln (replicated across g)
  float l_run = 0.f;

  const int tid = threadIdx.x;
  const int vr0 = (tid >> 3) * 2;   // key row pair
  const int vc0 = (tid & 7) * 8;    // dim cols
#define VSWZ(c) ((((c) ^ ((c) >> 3)) & 7) << 4)

  // prologue: stage tile kt0 into buffer 0
  {
    const u16* xsrc = Xb + ((size_t)b * S_LEN + kt0 * 64 + vr0) * DIM + h * 64 + vc0;
    bf16x8 r0 = *(const bf16x8*)xsrc;
    bf16x8 r1 = *(const bf16x8*)(xsrc + DIM);
#pragma unroll
    for (int rd = 0; rd < 2; ++rd) {
      int ch = rd * 4 + wave;
      int flat = ch * 1024 + lane * 16;
      int row = flat >> 7;
      int within = (flat & 127) ^ ((row & 7) << 4);
      g2l16((const char*)Q + (((size_t)b * S_LEN + kt0 * 64 + row) * DIM + h * 64) * 2 + within,
            (char*)Ks[0] + ch * 1024);
    }
#pragma unroll
    for (int j = 0; j < 8; ++j) {
      int c = vc0 + j;
      unsigned int pack = (unsigned int)(u16)r0[j] | ((unsigned int)(u16)r1[j] << 16);
      *(unsigned int*)((char*)Vt[0] + c * 128 + ((vr0 * 2) ^ VSWZ(c))) = pack;
    }
  }
  __syncthreads();

  for (int kt = kt0; kt < kt1e; ++kt) {
    const int cur = (kt - kt0) & 1, nxt = cur ^ 1;
    const bool more = (kt + 1 < kt1e);
    bf16x8 nr0, nr1;
    if (more) {
      const u16* xsrc = Xb + ((size_t)b * S_LEN + (kt + 1) * 64 + vr0) * DIM + h * 64 + vc0;
      nr0 = *(const bf16x8*)xsrc;
      nr1 = *(const bf16x8*)(xsrc + DIM);
#pragma unroll
      for (int rd = 0; rd < 2; ++rd) {
        int ch = rd * 4 + wave;
        int flat = ch * 1024 + lane * 16;
        int row = flat >> 7;
        int within = (flat & 127) ^ ((row & 7) << 4);
        g2l16((const char*)Q + (((size_t)b * S_LEN + (kt + 1) * 64 + row) * DIM + h * 64) * 2 + within,
              (char*)Ks[nxt] + ch * 1024);
      }
      __builtin_amdgcn_sched_barrier(0);
    }

    // QK^T SWAPPED: D[key][q]; lane holds key = sub*16 + g*4 + r, q = ln
    float pv_[4][4];
#pragma unroll
    for (int sub = 0; sub < 4; ++sub) {
      int kr = sub * 16 + ln;
      bf16x8 kb0 = *(const bf16x8*)((const char*)Ks[cur] + kr * 128 + ((g * 16) ^ ((kr & 7) << 4)));
      bf16x8 kb1 = *(const bf16x8*)((const char*)Ks[cur] + kr * 128 + ((64 + g * 16) ^ ((kr & 7) << 4)));
      f32x4 c = {};
      c = __builtin_amdgcn_mfma_f32_16x16x32_bf16(kb0, qa0, c, 0, 0, 0);
      c = __builtin_amdgcn_mfma_f32_16x16x32_bf16(kb1, qa1, c, 0, 0, 0);
      if (kt == qt) {
#pragma unroll
        for (int r = 0; r < 4; ++r) {
          int key = sub * 16 + g * 4 + r;
          int qi = wave * 16 + ln;
          pv_[sub][r] = (key > qi) ? -INFINITY : c[r];
        }
      } else {
#pragma unroll
        for (int r = 0; r < 4; ++r) pv_[sub][r] = c[r];
      }
    }

    // in-lane row max over this lane's 16 scores, then cross-g butterfly
    float pmax = pv_[0][0];
#pragma unroll
    for (int sub = 0; sub < 4; ++sub)
#pragma unroll
      for (int r = 0; r < 4; ++r) pmax = fmaxf(pmax, pv_[sub][r]);
    pmax = fmaxf(pmax, __shfl_xor(pmax, 16));
    pmax = fmaxf(pmax, __shfl_xor(pmax, 32));

    // defer-rescale (THR=8, log2 domain)
    if (!__all(pmax <= m_run + 8.0f)) {
      float m_new = fmaxf(m_run, pmax);
      float scl = exp2f(m_run - m_new);
      m_run = m_new;
      l_run *= scl;
#pragma unroll
      for (int r = 0; r < 4; ++r) {
        float s = __shfl(scl, g * 4 + r);
#pragma unroll
        for (int ns = 0; ns < 4; ++ns) acc[ns][r] *= s;
      }
    }

    float lsum = 0.f;
#pragma unroll
    for (int sub = 0; sub < 4; ++sub)
#pragma unroll
      for (int r = 0; r < 4; ++r) {
        pv_[sub][r] = exp2f(pv_[sub][r] - m_run);
        lsum += pv_[sub][r];
      }
    lsum += __shfl_xor(lsum, 16);
    lsum += __shfl_xor(lsum, 32);
    l_run += lsum;

    // P store: 4 key-consecutive bf16 per (lane,sub) -> one b64 each
#pragma unroll
    for (int sub = 0; sub < 4; ++sub) {
      uint2 val;
      val.x = (unsigned int)f2bfq(pv_[sub][0]) | ((unsigned int)f2bfq(pv_[sub][1]) << 16);
      val.y = (unsigned int)f2bfq(pv_[sub][2]) | ((unsigned int)f2bfq(pv_[sub][3]) << 16);
      *(uint2*)((char*)Pw[wave] + ln * 128 + ((sub * 32 + g * 8) ^ ((ln & 7) << 4))) = val;
    }

    bf16x8 pa0 = *(const bf16x8*)((const char*)Pw[wave] + ln * 128 + ((g * 16) ^ ((ln & 7) << 4)));
    bf16x8 pa1 = *(const bf16x8*)((const char*)Pw[wave] + ln * 128 + ((64 + g * 16) ^ ((ln & 7) << 4)));
#pragma unroll
    for (int ns = 0; ns < 4; ++ns) {
      int vr = ns * 16 + ln;
      bf16x8 vb0 = *(const bf16x8*)((const char*)Vt[cur] + vr * 128 + ((g * 16) ^ VSWZ(vr)));
      bf16x8 vb1 = *(const bf16x8*)((const char*)Vt[cur] + vr * 128 + ((64 + g * 16) ^ VSWZ(vr)));
      acc[ns] = __builtin_amdgcn_mfma_f32_16x16x32_bf16(pa0, vb0, acc[ns], 0, 0, 0);
      acc[ns] = __builtin_amdgcn_mfma_f32_16x16x32_bf16(pa1, vb1, acc[ns], 0, 0, 0);
    }

    if (more) {
#pragma unroll
      for (int j = 0; j < 8; ++j) {
        int c = vc0 + j;
        unsigned int pack = (unsigned int)(u16)nr0[j] | ((unsigned int)(u16)nr1[j] << 16);
        *(unsigned int*)((char*)Vt[nxt] + c * 128 + ((vr0 * 2) ^ VSWZ(c))) = pack;
      }
    }
    __syncthreads();
  }

  // write unnormalized bf16 partial ctx + stats (log2-domain m, l)
  const size_t slot = ((size_t)(b * NH + h)) * PARTS_PER_BH + p;
#pragma unroll
  for (int ns = 0; ns < 4; ++ns)
#pragma unroll
    for (int r = 0; r < 4; ++r) {
      int qr = wave * 16 + g * 4 + r;
      CTXP[slot * 4096 + (size_t)qr * 64 + ns * 16 + ln] = f2bfq(acc[ns][r]);
    }
  if (lane < 16) {
    MP[slot * 64 + wave * 16 + lane] = m_run;
    LP[slot * 64 + wave * 16 + lane] = l_run;
  }
}

// Merge K-chunk partials + fold L=4 memory slots (log2 domain), final bf16 ctx.
__global__ __launch_bounds__(256)
void finalize(const u16* __restrict__ Q, const float* __restrict__ PQ,
              const float* __restrict__ PV, const u16* __restrict__ CTXP,
              const float* __restrict__ MP, const float* __restrict__ LP,
              u16* __restrict__ Cout) {
  const int lane = threadIdx.x & 63, wave = threadIdx.x >> 6;
  const size_t row = (size_t)blockIdx.x * 4 + wave;  // (b*H+h)*S + s
  const int s = (int)(row & (S_LEN - 1));
  const int h = (int)((row >> 11) & (NH - 1));
  const int b = (int)(row >> 15);

  const int qt = s >> 6, G = qt >> 3, parts = G + 1;
  const int baseG[4] = {0, 8, 24, 48};
  const int p0 = baseG[G] + (qt & 7) * parts;
  const size_t slot0 = ((size_t)(b * NH + h)) * PARTS_PER_BH + p0;
  const int sr = s & 63;

  float mc[4], lc[4];
  float m_tok = -INFINITY;
#pragma unroll
  for (int c = 0; c < 4; ++c)
    if (c < parts) {
      mc[c] = MP[(slot0 + c) * 64 + sr];
      lc[c] = LP[(slot0 + c) * 64 + sr];
      m_tok = fmaxf(m_tok, mc[c]);
    }
  float l_tok = 0.f, cd = 0.f;
#pragma unroll
  for (int c = 0; c < 4; ++c)
    if (c < parts) {
      float w = exp2f(mc[c] - m_tok);
      l_tok += w * lc[c];
      cd += w * bf2f(CTXP[(slot0 + c) * 4096 + (size_t)sr * 64 + lane]);
    }

  // memory slots (qd carries one ALPHA; multiply by ALPHA for full scale)
  const float qd = bf2f(Q[((size_t)b * S_LEN + s) * DIM + h * 64 + lane]);
  const float* pq = PQ + row * (NL * 64);
  const float* pv = PV + row * (NL * 64);
  float msc[NL];
  float m_fin = m_tok;
#pragma unroll
  for (int lm = 0; lm < NL; ++lm) {
    float prod = qd * pq[lm * 64 + lane];
#pragma unroll
    for (int o = 1; o < 64; o <<= 1) prod += __shfl_xor(prod, o);
    msc[lm] = prod * ALPHA;
    m_fin = fmaxf(m_fin, msc[lm]);
  }
  const float a = exp2f(m_tok - m_fin);
  float l_fin = l_tok * a;
  cd *= a;
#pragma unroll
  for (int lm = 0; lm < NL; ++lm) {
    float w = exp2f(msc[lm] - m_fin);
    l_fin += w;
    cd += w * pv[lm * 64 + lane];
  }
  Cout[((size_t)b * S_LEN + s) * DIM + h * 64 + lane] = f2bf(cd / l_fin);
}

extern "C" void kernel_launch(void* const* d_in, const int* in_sizes, int n_in,
                              void* d_out, int out_size, void* d_ws, size_t ws_size,
                              hipStream_t stream) {
  const float* x  = (const float*)d_in[0];
  const float* pq = (const float*)d_in[1];
  const float* pv = (const float*)d_in[2];
  const float* Wq = (const float*)d_in[3];
  const float* bq = (const float*)d_in[4];
  const float* Wo = (const float*)d_in[5];
  const float* bo = (const float*)d_in[6];
  float* out = (float*)d_out;

  const int M = NB * S_LEN;  // 4096
  u16*   Qws  = (u16*)d_ws;                    // 8 MB (ALPHA-scaled Q, bf16)
  u16*   Cws  = Qws + (size_t)M * DIM;         // 8 MB
  u16*   xbf  = Cws + (size_t)M * DIM;         // 8 MB
  u16*   Wqbf = xbf + (size_t)M * DIM;         // 2 MB
  u16*   Wobf = Wqbf + (size_t)DIM * DIM;      // 2 MB
  u16*   CTXP = Wobf + (size_t)DIM * DIM;      // 2560 slots x 4096 bf16 = 21 MB
  float* MP   = (float*)(CTXP + (size_t)NB * NH * PARTS_PER_BH * 4096);  // 640 KB
  float* LP   = MP + (size_t)NB * NH * PARTS_PER_BH * 64;                // 640 KB

  const int n4x = M * DIM / 4, n4w = DIM * DIM / 4;
  cvt_all<<<(n4x + 2 * n4w + 255) / 256, 256, 0, stream>>>(
      x, Wq, Wo, xbf, Wqbf, Wobf, n4x, n4w);

  gemm_bt<false, u16><<<dim3(DIM / 64, M / 128), 256, 0, stream>>>(
      xbf, Wqbf, bq, Qws, M, DIM, DIM, ALPHA);
  attn<<<dim3(PARTS_PER_BH, NH, NB), 256, 0, stream>>>(Qws, xbf, CTXP, MP, LP);
  finalize<<<NB * NH * S_LEN / 4, 256, 0, stream>>>(Qws, pq, pv, CTXP, MP, LP, Cws);
  gemm_bt<true, float><<<dim3(DIM / 64, M / 128), 256, 0, stream>>>(
      Cws, Wobf, bo, out, M, DIM, DIM, 1.0f);
}

// Round 10
// 129.742 us; speedup vs baseline: 1.3594x; 1.0842x over previous
//
#include <hip/hip_runtime.h>
#include <hip/hip_bf16.h>
#include <math.h>

#define S_LEN 2048
#define DIM   1024
#define NH    16
#define NL    4
#define NB    2
#define PARTS_PER_BH 80   // sum over 32 q-tiles(64) of ceil((qt+1)/8)
#define ALPHA 0.42466086f // sqrt(0.125 * log2(e)); folded into Q

typedef __attribute__((ext_vector_type(8))) short bf16x8;
typedef __attribute__((ext_vector_type(4))) float f32x4;
typedef unsigned short u16;

template <int N> struct Tag { static constexpr int cur = N; };

__device__ __forceinline__ float bf2f(u16 u) {
  union { unsigned int i; float f; } x; x.i = ((unsigned int)u) << 16; return x.f;
}
__device__ __forceinline__ u16 f2bf(float f) {  // RNE, integer path
  union { float f; unsigned int i; } x; x.f = f;
  unsigned int r = x.i + 0x7fffu + ((x.i >> 16) & 1u);
  return (u16)(r >> 16);
}
__device__ __forceinline__ u16 f2bfq(float f) { // compiler cvt path
  __hip_bfloat16 h = __float2bfloat16(f);
  return *reinterpret_cast<u16*>(&h);
}

__device__ __forceinline__ void g2l16(const void* g, void* l) {
  __builtin_amdgcn_global_load_lds(
      (const __attribute__((address_space(1))) void*)g,
      (__attribute__((address_space(3))) void*)l, 16, 0, 0);
}

// gelu via tanh form, tanh via one exp2. |err vs exact erf-gelu| <= ~3e-4.
__device__ __forceinline__ float gelu_fast(float v) {
  float y = 0.79788456f * (v + 0.044715f * v * v * v);
  float e = exp2f(y * 2.88539008f);          // e^(2y)
  float t = 1.0f - 2.0f / (e + 1.0f);        // tanh(y)
  return 0.5f * v * (1.0f + t);
}

// One fused f32->bf16 convert for x, Wq, Wo.
__global__ __launch_bounds__(256)
void cvt_all(const float* __restrict__ x, const float* __restrict__ wq,
             const float* __restrict__ wo, u16* __restrict__ ox,
             u16* __restrict__ owq, u16* __restrict__ owo, int n4x, int n4w) {
  int i = blockIdx.x * blockDim.x + threadIdx.x;
  const float* src; u16* dst; int j;
  if (i < n4x)            { src = x;  dst = ox;  j = i; }
  else if (i < n4x + n4w) { src = wq; dst = owq; j = i - n4x; }
  else                    { src = wo; dst = owo; j = i - n4x - n4w;
                            if (j >= n4w) return; }
  float4 v = ((const float4*)src)[j];
  ushort4 o;
  o.x = f2bf(v.x); o.y = f2bf(v.y); o.z = f2bf(v.z); o.w = f2bf(v.w);
  ((ushort4*)dst)[j] = o;
}

// C = act(A @ Bt^T + bias) * oscale. 128x64 tile, BK=64, 4 waves (2x2).
// 2-phase pipeline: double-buffered LDS, stage(next) before compute(cur),
// ONE barrier per K-step. No XCD swizzle (L3-fit inputs: swizzle hurts).
template <bool GELU, typename OT>
__global__ __launch_bounds__(256)
void gemm_bt(const u16* __restrict__ A, const u16* __restrict__ Bt,
             const float* __restrict__ bias, OT* __restrict__ C,
             int M, int N, int K, float oscale) {
  __shared__ u16 As[2][128 * 64];
  __shared__ u16 Bs[2][64 * 64];
  const int lane = threadIdx.x & 63, wave = threadIdx.x >> 6;
  const int ln = lane & 15, g = lane >> 4;
  const int m0 = blockIdx.y * 128, n0 = blockIdx.x * 64;
  const int wm = wave >> 1, wn = wave & 1;
  f32x4 acc[4][2] = {};

  auto stage = [&](int buf, int k0) {
#pragma unroll
    for (int rd = 0; rd < 6; ++rd) {
      int ch = rd * 4 + wave;                   // 0..23: 16 A-chunks + 8 B-chunks
      if (ch < 16) {
        int flatb = ch * 1024 + lane * 16;
        int row = flatb >> 7;
        int within = (flatb & 127) ^ ((row & 7) << 4);
        g2l16((const char*)A + ((size_t)(m0 + row) * K + k0) * 2 + within,
              (char*)As[buf] + ch * 1024);
      } else {
        int flatb = (ch - 16) * 1024 + lane * 16;
        int row = flatb >> 7;
        int within = (flatb & 127) ^ ((row & 7) << 4);
        g2l16((const char*)Bt + ((size_t)(n0 + row) * K + k0) * 2 + within,
              (char*)Bs[buf] + (ch - 16) * 1024);
      }
    }
  };

  stage(0, 0);
  __syncthreads();
  const int NT = K / 64;
  for (int t = 0; t < NT; ++t) {
    const int cur = t & 1;
    if (t + 1 < NT) stage(cur ^ 1, (t + 1) * 64);
#pragma unroll
    for (int kc = 0; kc < 2; ++kc) {
      bf16x8 af[4], bfr[2];
#pragma unroll
      for (int i = 0; i < 4; ++i) {
        int ra = wm * 64 + i * 16 + ln;
        af[i] = *(const bf16x8*)((const char*)As[cur] + ra * 128 +
                                 ((kc * 64 + g * 16) ^ ((ra & 7) << 4)));
      }
#pragma unroll
      for (int j = 0; j < 2; ++j) {
        int rb = wn * 32 + j * 16 + ln;
        bfr[j] = *(const bf16x8*)((const char*)Bs[cur] + rb * 128 +
                                  ((kc * 64 + g * 16) ^ ((rb & 7) << 4)));
      }
#pragma unroll
      for (int i = 0; i < 4; ++i)
#pragma unroll
        for (int j = 0; j < 2; ++j)
          acc[i][j] = __builtin_amdgcn_mfma_f32_16x16x32_bf16(af[i], bfr[j], acc[i][j], 0, 0, 0);
    }
    __syncthreads();   // drains this iter's prefetch + fences buffer reuse
  }

#pragma unroll
  for (int j = 0; j < 2; ++j) {
    int gc = n0 + wn * 32 + j * 16 + ln;
    float bv = bias[gc];
#pragma unroll
    for (int i = 0; i < 4; ++i) {
      int gr0 = m0 + wm * 64 + i * 16 + g * 4;
#pragma unroll
      for (int r = 0; r < 4; ++r) {
        float v = acc[i][j][r] + bv;
        if constexpr (GELU) v = gelu_fast(v);
        v *= oscale;
        if constexpr (sizeof(OT) == 2) C[(size_t)(gr0 + r) * N + gc] = (OT)f2bf(v);
        else                           C[(size_t)(gr0 + r) * N + gc] = (OT)v;
      }
    }
  }
}

// Flash self-attention, token part, K-chunked. QBLK=64 (4 waves x 16 q-rows).
// Swapped QK^T (D[key][q], q=ln lane-local). All LDS byte offsets precomputed
// per-lane; buffer parity is a compile-time immediate (unroll-2 via Tag<CUR>);
// global staging pointers advance by constant stride. grid (PARTS_PER_BH,H,B).
__global__ __launch_bounds__(256, 4)
void attn(const u16* __restrict__ Q, const u16* __restrict__ Xb,
          u16* __restrict__ CTXP, float* __restrict__ MP, float* __restrict__ LP) {
  // layout: Ks0 @0, Ks1 @8192, Vt0 @16384, Vt1 @24576, Pw @32768 + wave*2048
  __shared__ __attribute__((aligned(16))) char lds[40960];

  const int lane = threadIdx.x & 63, wave = threadIdx.x >> 6;
  const int ln = lane & 15, g = lane >> 4;
  const int h = blockIdx.y, b = blockIdx.z;

  // part -> (qt, chunk); parts(qt) = ceil((qt+1)/8)
  const int p = blockIdx.x;
  int qt, chunk;
  if (p < 8)       { qt = p;                          chunk = 0; }
  else if (p < 24) { int i = p - 8;  qt = 8 + (i >> 1);  chunk = i & 1; }
  else if (p < 48) { int i = p - 24; qt = 16 + i / 3;    chunk = i % 3; }
  else             { int i = p - 48; qt = 24 + (i >> 2); chunk = i & 3; }
  const int kt0 = chunk * 8;
  const int kt1e = kt0 + 8 < qt + 1 ? kt0 + 8 : qt + 1;

  const size_t qrow = (size_t)b * S_LEN + qt * 64 + wave * 16 + ln;
  const bf16x8 qa0 = *(const bf16x8*)(Q + qrow * DIM + h * 64 + g * 8);
  const bf16x8 qa1 = *(const bf16x8*)(Q + qrow * DIM + h * 64 + 32 + g * 8);

  // ---- per-lane loop-invariant LDS byte offsets ----
  const int tid = threadIdx.x;
  const int vr0 = (tid >> 3) * 2;   // key row pair (V staging)
  const int vc0 = (tid & 7) * 8;    // dim cols     (V staging)
  const int t7 = tid & 7;
  const int sw7 = (ln & 7) << 4;
  const int kbase0 = ln * 128 + ((g * 16) ^ sw7);        // +cur*8192+sub*2048
  const int kbase1 = ln * 128 + ((64 + g * 16) ^ sw7);
  const int swb = (ln & 7) ^ (ln >> 3);
  int vrd0[4], vrd1[4];                                   // V reads (dim row ns*16+ln)
#pragma unroll
  for (int ns = 0; ns < 4; ++ns) {
    int sw = (swb ^ (ns * 2)) << 4;
    vrd0[ns] = ln * 128 + ((g * 16) ^ sw);
    vrd1[ns] = ln * 128 + ((64 + g * 16) ^ sw);
  }
  int vwr[8];                                             // V^T staging writes
#pragma unroll
  for (int j = 0; j < 8; ++j)
    vwr[j] = (vc0 + j) * 128 + ((vr0 * 2) ^ ((j ^ t7) << 4));
  int pst[4];                                             // P stores
#pragma unroll
  for (int sub = 0; sub < 4; ++sub)
    pst[sub] = 32768 + wave * 2048 + ln * 128 + ((sub * 32 + g * 8) ^ sw7);
  const int prd0 = 32768 + wave * 2048 + ln * 128 + ((g * 16) ^ sw7);
  const int prd1 = 32768 + wave * 2048 + ln * 128 + ((64 + g * 16) ^ sw7);
  int ksrc[2];                                            // K staging src voffsets
#pragma unroll
  for (int rd = 0; rd < 2; ++rd) {
    int ch = rd * 4 + wave;
    int flat = ch * 1024 + lane * 16;
    int row = flat >> 7;
    ksrc[rd] = row * (DIM * 2) + ((flat & 127) ^ ((row & 7) << 4));
  }

  // advancing global byte pointers (uniform stride per key-tile)
  const size_t STEP = (size_t)64 * DIM * 2;
  const char* kq = (const char*)(Q + ((size_t)b * S_LEN + (size_t)kt0 * 64) * DIM + h * 64);
  const char* xv = (const char*)(Xb + ((size_t)b * S_LEN + (size_t)kt0 * 64 + vr0) * DIM + h * 64 + vc0);

  f32x4 acc[4] = {};
  float m_run = -INFINITY;   // per-lane: q = ln (replicated across g)
  float l_run = 0.f;

  // prologue: stage tile kt0 into buffer 0
  {
    bf16x8 r0 = *(const bf16x8*)xv;
    bf16x8 r1 = *(const bf16x8*)(xv + DIM * 2);
#pragma unroll
    for (int rd = 0; rd < 2; ++rd)
      g2l16(kq + ksrc[rd], lds + (rd * 4 + wave) * 1024);
#pragma unroll
    for (int j = 0; j < 8; ++j) {
      unsigned int pack = (unsigned int)(u16)r0[j] | ((unsigned int)(u16)r1[j] << 16);
      *(unsigned int*)(lds + 16384 + vwr[j]) = pack;
    }
  }
  __syncthreads();

  int kt = kt0;
  auto body = [&](auto tag) {
    constexpr int CUR = decltype(tag)::cur;
    constexpr int NXT = CUR ^ 1;
    const bool more = (kt + 1 < kt1e);
    bf16x8 nr0, nr1;
    if (more) {
      const char* nxv = xv + STEP;
      nr0 = *(const bf16x8*)nxv;
      nr1 = *(const bf16x8*)(nxv + DIM * 2);
      const char* nkq = kq + STEP;
#pragma unroll
      for (int rd = 0; rd < 2; ++rd)
        g2l16(nkq + ksrc[rd], lds + NXT * 8192 + (rd * 4 + wave) * 1024);
      __builtin_amdgcn_sched_barrier(0);
    }

    // QK^T SWAPPED: D[key][q]; lane holds key = sub*16 + g*4 + r, q = ln
    float pv_[4][4];
    __builtin_amdgcn_s_setprio(1);
#pragma unroll
    for (int sub = 0; sub < 4; ++sub) {
      bf16x8 kb0 = *(const bf16x8*)(lds + CUR * 8192 + sub * 2048 + kbase0);
      bf16x8 kb1 = *(const bf16x8*)(lds + CUR * 8192 + sub * 2048 + kbase1);
      f32x4 c = {};
      c = __builtin_amdgcn_mfma_f32_16x16x32_bf16(kb0, qa0, c, 0, 0, 0);
      c = __builtin_amdgcn_mfma_f32_16x16x32_bf16(kb1, qa1, c, 0, 0, 0);
      if (kt == qt) {
#pragma unroll
        for (int r = 0; r < 4; ++r) {
          int key = sub * 16 + g * 4 + r;
          pv_[sub][r] = (key > wave * 16 + ln) ? -INFINITY : c[r];
        }
      } else {
#pragma unroll
        for (int r = 0; r < 4; ++r) pv_[sub][r] = c[r];
      }
    }
    __builtin_amdgcn_s_setprio(0);

    // in-lane row max over this lane's 16 scores, then cross-g butterfly
    float pmax = pv_[0][0];
#pragma unroll
    for (int sub = 0; sub < 4; ++sub)
#pragma unroll
      for (int r = 0; r < 4; ++r) pmax = fmaxf(pmax, pv_[sub][r]);
    pmax = fmaxf(pmax, __shfl_xor(pmax, 16));
    pmax = fmaxf(pmax, __shfl_xor(pmax, 32));

    // defer-rescale (THR=8, log2 domain)
    if (!__all(pmax <= m_run + 8.0f)) {
      float m_new = fmaxf(m_run, pmax);
      float scl = exp2f(m_run - m_new);
      m_run = m_new;
      l_run *= scl;
#pragma unroll
      for (int r = 0; r < 4; ++r) {
        float s = __shfl(scl, g * 4 + r);
#pragma unroll
        for (int ns = 0; ns < 4; ++ns) acc[ns][r] *= s;
      }
    }

    float lsum = 0.f;
#pragma unroll
    for (int sub = 0; sub < 4; ++sub)
#pragma unroll
      for (int r = 0; r < 4; ++r) {
        pv_[sub][r] = exp2f(pv_[sub][r] - m_run);
        lsum += pv_[sub][r];
      }
    lsum += __shfl_xor(lsum, 16);
    lsum += __shfl_xor(lsum, 32);
    l_run += lsum;

    // P store: 4 key-consecutive bf16 per (lane,sub) -> one b64 each
#pragma unroll
    for (int sub = 0; sub < 4; ++sub) {
      uint2 val;
      val.x = (unsigned int)f2bfq(pv_[sub][0]) | ((unsigned int)f2bfq(pv_[sub][1]) << 16);
      val.y = (unsigned int)f2bfq(pv_[sub][2]) | ((unsigned int)f2bfq(pv_[sub][3]) << 16);
      *(uint2*)(lds + pst[sub]) = val;
    }

    bf16x8 pa0 = *(const bf16x8*)(lds + prd0);
    bf16x8 pa1 = *(const bf16x8*)(lds + prd1);
    __builtin_amdgcn_s_setprio(1);
#pragma unroll
    for (int ns = 0; ns < 4; ++ns) {
      bf16x8 vb0 = *(const bf16x8*)(lds + 16384 + CUR * 8192 + ns * 2048 + vrd0[ns]);
      bf16x8 vb1 = *(const bf16x8*)(lds + 16384 + CUR * 8192 + ns * 2048 + vrd1[ns]);
      acc[ns] = __builtin_amdgcn_mfma_f32_16x16x32_bf16(pa0, vb0, acc[ns], 0, 0, 0);
      acc[ns] = __builtin_amdgcn_mfma_f32_16x16x32_bf16(pa1, vb1, acc[ns], 0, 0, 0);
    }
    __builtin_amdgcn_s_setprio(0);

    if (more) {
#pragma unroll
      for (int j = 0; j < 8; ++j) {
        unsigned int pack = (unsigned int)(u16)nr0[j] | ((unsigned int)(u16)nr1[j] << 16);
        *(unsigned int*)(lds + 16384 + NXT * 8192 + vwr[j]) = pack;
      }
    }
    __syncthreads();
    kq += STEP; xv += STEP;
  };

  for (;;) {
    body(Tag<0>{});
    if (++kt >= kt1e) break;
    body(Tag<1>{});
    if (++kt >= kt1e) break;
  }

  // write unnormalized bf16 partial ctx + stats (log2-domain m, l)
  const size_t slot = ((size_t)(b * NH + h)) * PARTS_PER_BH + p;
#pragma unroll
  for (int ns = 0; ns < 4; ++ns)
#pragma unroll
    for (int r = 0; r < 4; ++r) {
      int qr = wave * 16 + g * 4 + r;
      CTXP[slot * 4096 + (size_t)qr * 64 + ns * 16 + ln] = f2bfq(acc[ns][r]);
    }
  if (lane < 16) {
    MP[slot * 64 + wave * 16 + lane] = m_run;
    LP[slot * 64 + wave * 16 + lane] = l_run;
  }
}

// Merge K-chunk partials + fold L=4 memory slots (log2 domain), final bf16 ctx.
__global__ __launch_bounds__(256)
void finalize(const u16* __restrict__ Q, const float* __restrict__ PQ,
              const float* __restrict__ PV, const u16* __restrict__ CTXP,
              const float* __restrict__ MP, const float* __restrict__ LP,
              u16* __restrict__ Cout) {
  const int lane = threadIdx.x & 63, wave = threadIdx.x >> 6;
  const size_t row = (size_t)blockIdx.x * 4 + wave;  // (b*H+h)*S + s
  const int s = (int)(row & (S_LEN - 1));
  const int h = (int)((row >> 11) & (NH - 1));
  const int b = (int)(row >> 15);

  const int qt = s >> 6, G = qt >> 3, parts = G + 1;
  const int baseG[4] = {0, 8, 24, 48};
  const int p0 = baseG[G] + (qt & 7) * parts;
  const size_t slot0 = ((size_t)(b * NH + h)) * PARTS_PER_BH + p0;
  const int sr = s & 63;

  float mc[4], lc[4];
  float m_tok = -INFINITY;
#pragma unroll
  for (int c = 0; c < 4; ++c)
    if (c < parts) {
      mc[c] = MP[(slot0 + c) * 64 + sr];
      lc[c] = LP[(slot0 + c) * 64 + sr];
      m_tok = fmaxf(m_tok, mc[c]);
    }
  float l_tok = 0.f, cd = 0.f;
#pragma unroll
  for (int c = 0; c < 4; ++c)
    if (c < parts) {
      float w = exp2f(mc[c] - m_tok);
      l_tok += w * lc[c];
      cd += w * bf2f(CTXP[(slot0 + c) * 4096 + (size_t)sr * 64 + lane]);
    }

  // memory slots (qd carries one ALPHA; multiply by ALPHA for full scale)
  const float qd = bf2f(Q[((size_t)b * S_LEN + s) * DIM + h * 64 + lane]);
  const float* pq = PQ + row * (NL * 64);
  const float* pv = PV + row * (NL * 64);
  float msc[NL];
  float m_fin = m_tok;
#pragma unroll
  for (int lm = 0; lm < NL; ++lm) {
    float prod = qd * pq[lm * 64 + lane];
#pragma unroll
    for (int o = 1; o < 64; o <<= 1) prod += __shfl_xor(prod, o);
    msc[lm] = prod * ALPHA;
    m_fin = fmaxf(m_fin, msc[lm]);
  }
  const float a = exp2f(m_tok - m_fin);
  float l_fin = l_tok * a;
  cd *= a;
#pragma unroll
  for (int lm = 0; lm < NL; ++lm) {
    float w = exp2f(msc[lm] - m_fin);
    l_fin += w;
    cd += w * pv[lm * 64 + lane];
  }
  Cout[((size_t)b * S_LEN + s) * DIM + h * 64 + lane] = f2bf(cd / l_fin);
}

extern "C" void kernel_launch(void* const* d_in, const int* in_sizes, int n_in,
                              void* d_out, int out_size, void* d_ws, size_t ws_size,
                              hipStream_t stream) {
  const float* x  = (const float*)d_in[0];
  const float* pq = (const float*)d_in[1];
  const float* pv = (const float*)d_in[2];
  const float* Wq = (const float*)d_in[3];
  const float* bq = (const float*)d_in[4];
  const float* Wo = (const float*)d_in[5];
  const float* bo = (const float*)d_in[6];
  float* out = (float*)d_out;

  const int M = NB * S_LEN;  // 4096
  u16*   Qws  = (u16*)d_ws;                    // 8 MB (ALPHA-scaled Q, bf16)
  u16*   Cws  = Qws + (size_t)M * DIM;         // 8 MB
  u16*   xbf  = Cws + (size_t)M * DIM;         // 8 MB
  u16*   Wqbf = xbf + (size_t)M * DIM;         // 2 MB
  u16*   Wobf = Wqbf + (size_t)DIM * DIM;      // 2 MB
  u16*   CTXP = Wobf + (size_t)DIM * DIM;      // 2560 slots x 4096 bf16 = 21 MB
  float* MP   = (float*)(CTXP + (size_t)NB * NH * PARTS_PER_BH * 4096);  // 640 KB
  float* LP   = MP + (size_t)NB * NH * PARTS_PER_BH * 64;                // 640 KB

  const int n4x = M * DIM / 4, n4w = DIM * DIM / 4;
  cvt_all<<<(n4x + 2 * n4w + 255) / 256, 256, 0, stream>>>(
      x, Wq, Wo, xbf, Wqbf, Wobf, n4x, n4w);

  gemm_bt<false, u16><<<dim3(DIM / 64, M / 128), 256, 0, stream>>>(
      xbf, Wqbf, bq, Qws, M, DIM, DIM, ALPHA);
  attn<<<dim3(PARTS_PER_BH, NH, NB), 256, 0, stream>>>(Qws, xbf, CTXP, MP, LP);
  finalize<<<NB * NH * S_LEN / 4, 256, 0, stream>>>(Qws, pq, pv, CTXP, MP, LP, Cws);
  gemm_bt<true, float><<<dim3(DIM / 64, M / 128), 256, 0, stream>>>(
      Cws, Wobf, bo, out, M, DIM, DIM, 1.0f);
}

// Round 11
// 127.552 us; speedup vs baseline: 1.3828x; 1.0172x over previous
//
#include <hip/hip_runtime.h>
#include <hip/hip_bf16.h>
#include <math.h>

#define S_LEN 2048
#define DIM   1024
#define NH    16
#define NL    4
#define NB    2
#define PARTS_PER_BH 80   // sum over 32 q-tiles(64) of ceil((qt+1)/8)
#define ALPHA 0.42466086f // sqrt(0.125 * log2(e)); folded into Q

typedef __attribute__((ext_vector_type(8))) short bf16x8;
typedef __attribute__((ext_vector_type(4))) float f32x4;
typedef unsigned short u16;

template <int N> struct Tag { static constexpr int cur = N; };

__device__ __forceinline__ float bf2f(u16 u) {
  union { unsigned int i; float f; } x; x.i = ((unsigned int)u) << 16; return x.f;
}
__device__ __forceinline__ u16 f2bf(float f) {  // RNE, integer path
  union { float f; unsigned int i; } x; x.f = f;
  unsigned int r = x.i + 0x7fffu + ((x.i >> 16) & 1u);
  return (u16)(r >> 16);
}
__device__ __forceinline__ u16 f2bfq(float f) { // compiler cvt path
  __hip_bfloat16 h = __float2bfloat16(f);
  return *reinterpret_cast<u16*>(&h);
}

__device__ __forceinline__ void g2l16(const void* g, void* l) {
  __builtin_amdgcn_global_load_lds(
      (const __attribute__((address_space(1))) void*)g,
      (__attribute__((address_space(3))) void*)l, 16, 0, 0);
}

// DPP 16-lane butterfly sum (VALU-speed; controls verified in R3-R5).
template <int CTRL>
__device__ __forceinline__ float dppf(float x) {
  union { float f; int i; } u, r;
  u.f = x;
  r.i = __builtin_amdgcn_update_dpp(0, u.i, CTRL, 0xF, 0xF, true);
  return r.f;
}
__device__ __forceinline__ float rsum16(float x) {
  x += dppf<0xB1>(x);
  x += dppf<0x4E>(x);
  x += dppf<0x141>(x);
  x += dppf<0x140>(x);
  return x;
}

// gelu via tanh form, tanh via one exp2. |err vs exact erf-gelu| <= ~3e-4.
__device__ __forceinline__ float gelu_fast(float v) {
  float y = 0.79788456f * (v + 0.044715f * v * v * v);
  float e = exp2f(y * 2.88539008f);          // e^(2y)
  float t = 1.0f - 2.0f / (e + 1.0f);        // tanh(y)
  return 0.5f * v * (1.0f + t);
}

// One fused f32->bf16 convert for x, Wq, Wo.
__global__ __launch_bounds__(256)
void cvt_all(const float* __restrict__ x, const float* __restrict__ wq,
             const float* __restrict__ wo, u16* __restrict__ ox,
             u16* __restrict__ owq, u16* __restrict__ owo, int n4x, int n4w) {
  int i = blockIdx.x * blockDim.x + threadIdx.x;
  const float* src; u16* dst; int j;
  if (i < n4x)            { src = x;  dst = ox;  j = i; }
  else if (i < n4x + n4w) { src = wq; dst = owq; j = i - n4x; }
  else                    { src = wo; dst = owo; j = i - n4x - n4w;
                            if (j >= n4w) return; }
  float4 v = ((const float4*)src)[j];
  ushort4 o;
  o.x = f2bf(v.x); o.y = f2bf(v.y); o.z = f2bf(v.z); o.w = f2bf(v.w);
  ((ushort4*)dst)[j] = o;
}

// C = act(A @ Bt^T + bias) * oscale. 128x64 tile, BK=64, 4 waves (2x2).
// 2-phase pipeline: double-buffered LDS, stage(next) before compute(cur),
// ONE barrier per K-step. No XCD swizzle (L3-fit inputs: swizzle hurts).
template <bool GELU, typename OT>
__global__ __launch_bounds__(256)
void gemm_bt(const u16* __restrict__ A, const u16* __restrict__ Bt,
             const float* __restrict__ bias, OT* __restrict__ C,
             int M, int N, int K, float oscale) {
  __shared__ u16 As[2][128 * 64];
  __shared__ u16 Bs[2][64 * 64];
  const int lane = threadIdx.x & 63, wave = threadIdx.x >> 6;
  const int ln = lane & 15, g = lane >> 4;
  const int m0 = blockIdx.y * 128, n0 = blockIdx.x * 64;
  const int wm = wave >> 1, wn = wave & 1;
  f32x4 acc[4][2] = {};

  auto stage = [&](int buf, int k0) {
#pragma unroll
    for (int rd = 0; rd < 6; ++rd) {
      int ch = rd * 4 + wave;                   // 0..23: 16 A-chunks + 8 B-chunks
      if (ch < 16) {
        int flatb = ch * 1024 + lane * 16;
        int row = flatb >> 7;
        int within = (flatb & 127) ^ ((row & 7) << 4);
        g2l16((const char*)A + ((size_t)(m0 + row) * K + k0) * 2 + within,
              (char*)As[buf] + ch * 1024);
      } else {
        int flatb = (ch - 16) * 1024 + lane * 16;
        int row = flatb >> 7;
        int within = (flatb & 127) ^ ((row & 7) << 4);
        g2l16((const char*)Bt + ((size_t)(n0 + row) * K + k0) * 2 + within,
              (char*)Bs[buf] + (ch - 16) * 1024);
      }
    }
  };

  stage(0, 0);
  __syncthreads();
  const int NT = K / 64;
  for (int t = 0; t < NT; ++t) {
    const int cur = t & 1;
    if (t + 1 < NT) stage(cur ^ 1, (t + 1) * 64);
#pragma unroll
    for (int kc = 0; kc < 2; ++kc) {
      bf16x8 af[4], bfr[2];
#pragma unroll
      for (int i = 0; i < 4; ++i) {
        int ra = wm * 64 + i * 16 + ln;
        af[i] = *(const bf16x8*)((const char*)As[cur] + ra * 128 +
                                 ((kc * 64 + g * 16) ^ ((ra & 7) << 4)));
      }
#pragma unroll
      for (int j = 0; j < 2; ++j) {
        int rb = wn * 32 + j * 16 + ln;
        bfr[j] = *(const bf16x8*)((const char*)Bs[cur] + rb * 128 +
                                  ((kc * 64 + g * 16) ^ ((rb & 7) << 4)));
      }
#pragma unroll
      for (int i = 0; i < 4; ++i)
#pragma unroll
        for (int j = 0; j < 2; ++j)
          acc[i][j] = __builtin_amdgcn_mfma_f32_16x16x32_bf16(af[i], bfr[j], acc[i][j], 0, 0, 0);
    }
    __syncthreads();   // drains this iter's prefetch + fences buffer reuse
  }

#pragma unroll
  for (int j = 0; j < 2; ++j) {
    int gc = n0 + wn * 32 + j * 16 + ln;
    float bv = bias[gc];
#pragma unroll
    for (int i = 0; i < 4; ++i) {
      int gr0 = m0 + wm * 64 + i * 16 + g * 4;
#pragma unroll
      for (int r = 0; r < 4; ++r) {
        float v = acc[i][j][r] + bv;
        if constexpr (GELU) v = gelu_fast(v);
        v *= oscale;
        if constexpr (sizeof(OT) == 2) C[(size_t)(gr0 + r) * N + gc] = (OT)f2bf(v);
        else                           C[(size_t)(gr0 + r) * N + gc] = (OT)v;
      }
    }
  }
}

// Flash self-attention, token part, K-chunked. QBLK=64 (4 waves x 16 q-rows).
// Swapped QK^T (D[key][q], q=ln lane-local); precomputed LDS offsets;
// compile-time buffer parity (Tag unroll-2). Balanced equal-length key chunks
// + longest-first dispatch for occupancy. grid (PARTS_PER_BH, H, B).
__global__ __launch_bounds__(256, 4)
void attn(const u16* __restrict__ Q, const u16* __restrict__ Xb,
          u16* __restrict__ CTXP, float* __restrict__ MP, float* __restrict__ LP) {
  // layout: Ks0 @0, Ks1 @8192, Vt0 @16384, Vt1 @24576, Pw @32768 + wave*2048
  __shared__ __attribute__((aligned(16))) char lds[40960];

  const int lane = threadIdx.x & 63, wave = threadIdx.x >> 6;
  const int ln = lane & 15, g = lane >> 4;
  const int h = blockIdx.y, b = blockIdx.z;

  // longest-first: blockIdx 0 -> logical part 79 (qt=31), runts last
  const int pl = PARTS_PER_BH - 1 - blockIdx.x;
  int qt, chunk;
  if (pl < 8)       { qt = pl;                           chunk = 0; }
  else if (pl < 24) { int i = pl - 8;  qt = 8 + (i >> 1);  chunk = i & 1; }
  else if (pl < 48) { int i = pl - 24; qt = 16 + i / 3;    chunk = i % 3; }
  else              { int i = pl - 48; qt = 24 + (i >> 2); chunk = i & 3; }
  // balanced chunk bounds: lengths differ by <=1 (no 1-iter runts)
  const int len = qt + 1;
  const int parts = (len + 7) >> 3;
  const int kt0 = (chunk * len) / parts;
  const int kt1e = ((chunk + 1) * len) / parts;

  const size_t qrow = (size_t)b * S_LEN + qt * 64 + wave * 16 + ln;
  const bf16x8 qa0 = *(const bf16x8*)(Q + qrow * DIM + h * 64 + g * 8);
  const bf16x8 qa1 = *(const bf16x8*)(Q + qrow * DIM + h * 64 + 32 + g * 8);

  // ---- per-lane loop-invariant LDS byte offsets ----
  const int tid = threadIdx.x;
  const int vr0 = (tid >> 3) * 2;   // key row pair (V staging)
  const int vc0 = (tid & 7) * 8;    // dim cols     (V staging)
  const int t7 = tid & 7;
  const int sw7 = (ln & 7) << 4;
  const int kbase0 = ln * 128 + ((g * 16) ^ sw7);        // +cur*8192+sub*2048
  const int kbase1 = ln * 128 + ((64 + g * 16) ^ sw7);
  const int swb = (ln & 7) ^ (ln >> 3);
  int vrd0[4], vrd1[4];                                   // V reads (dim row ns*16+ln)
#pragma unroll
  for (int ns = 0; ns < 4; ++ns) {
    int sw = (swb ^ (ns * 2)) << 4;
    vrd0[ns] = ln * 128 + ((g * 16) ^ sw);
    vrd1[ns] = ln * 128 + ((64 + g * 16) ^ sw);
  }
  int vwr[8];                                             // V^T staging writes
#pragma unroll
  for (int j = 0; j < 8; ++j)
    vwr[j] = (vc0 + j) * 128 + ((vr0 * 2) ^ ((j ^ t7) << 4));
  int pst[4];                                             // P stores
#pragma unroll
  for (int sub = 0; sub < 4; ++sub)
    pst[sub] = 32768 + wave * 2048 + ln * 128 + ((sub * 32 + g * 8) ^ sw7);
  const int prd0 = 32768 + wave * 2048 + ln * 128 + ((g * 16) ^ sw7);
  const int prd1 = 32768 + wave * 2048 + ln * 128 + ((64 + g * 16) ^ sw7);
  int ksrc[2];                                            // K staging src voffsets
#pragma unroll
  for (int rd = 0; rd < 2; ++rd) {
    int ch = rd * 4 + wave;
    int flat = ch * 1024 + lane * 16;
    int row = flat >> 7;
    ksrc[rd] = row * (DIM * 2) + ((flat & 127) ^ ((row & 7) << 4));
  }

  // advancing global byte pointers (uniform stride per key-tile)
  const size_t STEP = (size_t)64 * DIM * 2;
  const char* kq = (const char*)(Q + ((size_t)b * S_LEN + (size_t)kt0 * 64) * DIM + h * 64);
  const char* xv = (const char*)(Xb + ((size_t)b * S_LEN + (size_t)kt0 * 64 + vr0) * DIM + h * 64 + vc0);

  f32x4 acc[4] = {};
  float m_run = -INFINITY;   // per-lane: q = ln (replicated across g)
  float l_run = 0.f;

  // prologue: stage tile kt0 into buffer 0
  {
    bf16x8 r0 = *(const bf16x8*)xv;
    bf16x8 r1 = *(const bf16x8*)(xv + DIM * 2);
#pragma unroll
    for (int rd = 0; rd < 2; ++rd)
      g2l16(kq + ksrc[rd], lds + (rd * 4 + wave) * 1024);
#pragma unroll
    for (int j = 0; j < 8; ++j) {
      unsigned int pack = (unsigned int)(u16)r0[j] | ((unsigned int)(u16)r1[j] << 16);
      *(unsigned int*)(lds + 16384 + vwr[j]) = pack;
    }
  }
  __syncthreads();

  int kt = kt0;
  auto body = [&](auto tag) {
    constexpr int CUR = decltype(tag)::cur;
    constexpr int NXT = CUR ^ 1;
    const bool more = (kt + 1 < kt1e);
    bf16x8 nr0, nr1;
    if (more) {
      const char* nxv = xv + STEP;
      nr0 = *(const bf16x8*)nxv;
      nr1 = *(const bf16x8*)(nxv + DIM * 2);
      const char* nkq = kq + STEP;
#pragma unroll
      for (int rd = 0; rd < 2; ++rd)
        g2l16(nkq + ksrc[rd], lds + NXT * 8192 + (rd * 4 + wave) * 1024);
      __builtin_amdgcn_sched_barrier(0);
    }

    // QK^T SWAPPED: D[key][q]; lane holds key = sub*16 + g*4 + r, q = ln
    float pv_[4][4];
    __builtin_amdgcn_s_setprio(1);
#pragma unroll
    for (int sub = 0; sub < 4; ++sub) {
      bf16x8 kb0 = *(const bf16x8*)(lds + CUR * 8192 + sub * 2048 + kbase0);
      bf16x8 kb1 = *(const bf16x8*)(lds + CUR * 8192 + sub * 2048 + kbase1);
      f32x4 c = {};
      c = __builtin_amdgcn_mfma_f32_16x16x32_bf16(kb0, qa0, c, 0, 0, 0);
      c = __builtin_amdgcn_mfma_f32_16x16x32_bf16(kb1, qa1, c, 0, 0, 0);
      if (kt == qt) {
#pragma unroll
        for (int r = 0; r < 4; ++r) {
          int key = sub * 16 + g * 4 + r;
          pv_[sub][r] = (key > wave * 16 + ln) ? -INFINITY : c[r];
        }
      } else {
#pragma unroll
        for (int r = 0; r < 4; ++r) pv_[sub][r] = c[r];
      }
    }
    __builtin_amdgcn_s_setprio(0);

    // in-lane row max over this lane's 16 scores, then cross-g butterfly
    float pmax = pv_[0][0];
#pragma unroll
    for (int sub = 0; sub < 4; ++sub)
#pragma unroll
      for (int r = 0; r < 4; ++r) pmax = fmaxf(pmax, pv_[sub][r]);
    pmax = fmaxf(pmax, __shfl_xor(pmax, 16));
    pmax = fmaxf(pmax, __shfl_xor(pmax, 32));

    // defer-rescale (THR=8, log2 domain)
    if (!__all(pmax <= m_run + 8.0f)) {
      float m_new = fmaxf(m_run, pmax);
      float scl = exp2f(m_run - m_new);
      m_run = m_new;
      l_run *= scl;
#pragma unroll
      for (int r = 0; r < 4; ++r) {
        float s = __shfl(scl, g * 4 + r);
#pragma unroll
        for (int ns = 0; ns < 4; ++ns) acc[ns][r] *= s;
      }
    }

    float lsum = 0.f;
#pragma unroll
    for (int sub = 0; sub < 4; ++sub)
#pragma unroll
      for (int r = 0; r < 4; ++r) {
        pv_[sub][r] = exp2f(pv_[sub][r] - m_run);
        lsum += pv_[sub][r];
      }
    lsum += __shfl_xor(lsum, 16);
    lsum += __shfl_xor(lsum, 32);
    l_run += lsum;

    // P store: 4 key-consecutive bf16 per (lane,sub) -> one b64 each
#pragma unroll
    for (int sub = 0; sub < 4; ++sub) {
      uint2 val;
      val.x = (unsigned int)f2bfq(pv_[sub][0]) | ((unsigned int)f2bfq(pv_[sub][1]) << 16);
      val.y = (unsigned int)f2bfq(pv_[sub][2]) | ((unsigned int)f2bfq(pv_[sub][3]) << 16);
      *(uint2*)(lds + pst[sub]) = val;
    }

    bf16x8 pa0 = *(const bf16x8*)(lds + prd0);
    bf16x8 pa1 = *(const bf16x8*)(lds + prd1);
    __builtin_amdgcn_s_setprio(1);
#pragma unroll
    for (int ns = 0; ns < 4; ++ns) {
      bf16x8 vb0 = *(const bf16x8*)(lds + 16384 + CUR * 8192 + ns * 2048 + vrd0[ns]);
      bf16x8 vb1 = *(const bf16x8*)(lds + 16384 + CUR * 8192 + ns * 2048 + vrd1[ns]);
      acc[ns] = __builtin_amdgcn_mfma_f32_16x16x32_bf16(pa0, vb0, acc[ns], 0, 0, 0);
      acc[ns] = __builtin_amdgcn_mfma_f32_16x16x32_bf16(pa1, vb1, acc[ns], 0, 0, 0);
    }
    __builtin_amdgcn_s_setprio(0);

    if (more) {
#pragma unroll
      for (int j = 0; j < 8; ++j) {
        unsigned int pack = (unsigned int)(u16)nr0[j] | ((unsigned int)(u16)nr1[j] << 16);
        *(unsigned int*)(lds + 16384 + NXT * 8192 + vwr[j]) = pack;
      }
    }
    __syncthreads();
    kq += STEP; xv += STEP;
  };

  for (;;) {
    body(Tag<0>{});
    if (++kt >= kt1e) break;
    body(Tag<1>{});
    if (++kt >= kt1e) break;
  }

  // write unnormalized bf16 partial ctx + stats (log2-domain m, l)
  const size_t slot = ((size_t)(b * NH + h)) * PARTS_PER_BH + pl;
#pragma unroll
  for (int ns = 0; ns < 4; ++ns)
#pragma unroll
    for (int r = 0; r < 4; ++r) {
      int qr = wave * 16 + g * 4 + r;
      CTXP[slot * 4096 + (size_t)qr * 64 + ns * 16 + ln] = f2bfq(acc[ns][r]);
    }
  if (lane < 16) {
    MP[slot * 64 + wave * 16 + lane] = m_run;
    LP[slot * 64 + wave * 16 + lane] = l_run;
  }
}

// Merge K-chunk partials + fold L=4 memory slots (log2 domain), final bf16 ctx.
// One wave per row; slot dots computed group-parallel (group g -> slot g):
// float4/ushort4 loads + 4-step DPP reduce + 4 broadcasts.
__global__ __launch_bounds__(256)
void finalize(const u16* __restrict__ Q, const float* __restrict__ PQ,
              const float* __restrict__ PV, const u16* __restrict__ CTXP,
              const float* __restrict__ MP, const float* __restrict__ LP,
              u16* __restrict__ Cout) {
  const int lane = threadIdx.x & 63, wave = threadIdx.x >> 6;
  const int ln = lane & 15, g = lane >> 4;
  const size_t row = (size_t)blockIdx.x * 4 + wave;  // (b*H+h)*S + s
  const int s = (int)(row & (S_LEN - 1));
  const int h = (int)((row >> 11) & (NH - 1));
  const int b = (int)(row >> 15);

  const int qt = s >> 6, G = qt >> 3, parts = G + 1;
  const int baseG[4] = {0, 8, 24, 48};
  const int p0 = baseG[G] + (qt & 7) * parts;
  const size_t slot0 = ((size_t)(b * NH + h)) * PARTS_PER_BH + p0;
  const int sr = s & 63;

  // group-parallel memory-slot dots: group g handles slot lm=g
  const float* pq = PQ + row * (NL * 64);
  const float* pv = PV + row * (NL * 64);
  ushort4 qu = *(const ushort4*)(Q + ((size_t)b * S_LEN + s) * DIM + h * 64 + ln * 4);
  float4 pqv = *(const float4*)(pq + g * 64 + ln * 4);
  float prod = bf2f(qu.x) * pqv.x + bf2f(qu.y) * pqv.y +
               bf2f(qu.z) * pqv.z + bf2f(qu.w) * pqv.w;
  prod = rsum16(prod);

  float mc[4], lc[4];
  float m_tok = -INFINITY;
#pragma unroll
  for (int c = 0; c < 4; ++c)
    if (c < parts) {
      mc[c] = MP[(slot0 + c) * 64 + sr];
      lc[c] = LP[(slot0 + c) * 64 + sr];
      m_tok = fmaxf(m_tok, mc[c]);
    }
  float l_tok = 0.f, cd = 0.f;
#pragma unroll
  for (int c = 0; c < 4; ++c)
    if (c < parts) {
      float w = exp2f(mc[c] - m_tok);
      l_tok += w * lc[c];
      cd += w * bf2f(CTXP[(slot0 + c) * 4096 + (size_t)sr * 64 + lane]);
    }

  float msc[NL];
  float m_fin = m_tok;
#pragma unroll
  for (int lm = 0; lm < NL; ++lm) {
    msc[lm] = __shfl(prod, lm << 4) * ALPHA;
    m_fin = fmaxf(m_fin, msc[lm]);
  }
  const float a = exp2f(m_tok - m_fin);
  float l_fin = l_tok * a;
  cd *= a;
#pragma unroll
  for (int lm = 0; lm < NL; ++lm) {
    float w = exp2f(msc[lm] - m_fin);
    l_fin += w;
    cd += w * pv[lm * 64 + lane];
  }
  Cout[((size_t)b * S_LEN + s) * DIM + h * 64 + lane] = f2bf(cd / l_fin);
}

extern "C" void kernel_launch(void* const* d_in, const int* in_sizes, int n_in,
                              void* d_out, int out_size, void* d_ws, size_t ws_size,
                              hipStream_t stream) {
  const float* x  = (const float*)d_in[0];
  const float* pq = (const float*)d_in[1];
  const float* pv = (const float*)d_in[2];
  const float* Wq = (const float*)d_in[3];
  const float* bq = (const float*)d_in[4];
  const float* Wo = (const float*)d_in[5];
  const float* bo = (const float*)d_in[6];
  float* out = (float*)d_out;

  const int M = NB * S_LEN;  // 4096
  u16*   Qws  = (u16*)d_ws;                    // 8 MB (ALPHA-scaled Q, bf16)
  u16*   Cws  = Qws + (size_t)M * DIM;         // 8 MB
  u16*   xbf  = Cws + (size_t)M * DIM;         // 8 MB
  u16*   Wqbf = xbf + (size_t)M * DIM;         // 2 MB
  u16*   Wobf = Wqbf + (size_t)DIM * DIM;      // 2 MB
  u16*   CTXP = Wobf + (size_t)DIM * DIM;      // 2560 slots x 4096 bf16 = 21 MB
  float* MP   = (float*)(CTXP + (size_t)NB * NH * PARTS_PER_BH * 4096);  // 640 KB
  float* LP   = MP + (size_t)NB * NH * PARTS_PER_BH * 64;                // 640 KB

  const int n4x = M * DIM / 4, n4w = DIM * DIM / 4;
  cvt_all<<<(n4x + 2 * n4w + 255) / 256, 256, 0, stream>>>(
      x, Wq, Wo, xbf, Wqbf, Wobf, n4x, n4w);

  gemm_bt<false, u16><<<dim3(DIM / 64, M / 128), 256, 0, stream>>>(
      xbf, Wqbf, bq, Qws, M, DIM, DIM, ALPHA);
  attn<<<dim3(PARTS_PER_BH, NH, NB), 256, 0, stream>>>(Qws, xbf, CTXP, MP, LP);
  finalize<<<NB * NH * S_LEN / 4, 256, 0, stream>>>(Qws, pq, pv, CTXP, MP, LP, Cws);
  gemm_bt<true, float><<<dim3(DIM / 64, M / 128), 256, 0, stream>>>(
      Cws, Wobf, bo, out, M, DIM, DIM, 1.0f);
}

// Round 12
// 121.965 us; speedup vs baseline: 1.4461x; 1.0458x over previous
//
#include <hip/hip_runtime.h>
#include <hip/hip_bf16.h>
#include <math.h>

#define S_LEN 2048
#define DIM   1024
#define NH    16
#define NL    4
#define NB    2
#define PARTS_PER_BH 80   // sum over 32 q-tiles(64) of ceil((qt+1)/8)
#define ALPHA 0.42466086f // sqrt(0.125 * log2(e)); folded into Q

typedef __attribute__((ext_vector_type(8))) short bf16x8;
typedef __attribute__((ext_vector_type(4))) float f32x4;
typedef unsigned short u16;

template <int N> struct Tag { static constexpr int cur = N; };

__device__ __forceinline__ float bf2f(u16 u) {
  union { unsigned int i; float f; } x; x.i = ((unsigned int)u) << 16; return x.f;
}
__device__ __forceinline__ u16 f2bf(float f) {  // RNE, integer path
  union { float f; unsigned int i; } x; x.f = f;
  unsigned int r = x.i + 0x7fffu + ((x.i >> 16) & 1u);
  return (u16)(r >> 16);
}
__device__ __forceinline__ u16 f2bfq(float f) { // compiler cvt path
  __hip_bfloat16 h = __float2bfloat16(f);
  return *reinterpret_cast<u16*>(&h);
}

__device__ __forceinline__ void g2l16(const void* g, void* l) {
  __builtin_amdgcn_global_load_lds(
      (const __attribute__((address_space(1))) void*)g,
      (__attribute__((address_space(3))) void*)l, 16, 0, 0);
}

// DPP 16-lane butterfly sum (VALU-speed; controls verified in R3-R11).
template <int CTRL>
__device__ __forceinline__ float dppf(float x) {
  union { float f; int i; } u, r;
  u.f = x;
  r.i = __builtin_amdgcn_update_dpp(0, u.i, CTRL, 0xF, 0xF, true);
  return r.f;
}
__device__ __forceinline__ float rsum16(float x) {
  x += dppf<0xB1>(x);
  x += dppf<0x4E>(x);
  x += dppf<0x141>(x);
  x += dppf<0x140>(x);
  return x;
}

// gelu via tanh form, tanh via one exp2. |err vs exact erf-gelu| <= ~3e-4.
__device__ __forceinline__ float gelu_fast(float v) {
  float y = 0.79788456f * (v + 0.044715f * v * v * v);
  float e = exp2f(y * 2.88539008f);          // e^(2y)
  float t = 1.0f - 2.0f / (e + 1.0f);        // tanh(y)
  return 0.5f * v * (1.0f + t);
}

// One fused f32->bf16 convert for x, Wq, Wo.
__global__ __launch_bounds__(256)
void cvt_all(const float* __restrict__ x, const float* __restrict__ wq,
             const float* __restrict__ wo, u16* __restrict__ ox,
             u16* __restrict__ owq, u16* __restrict__ owo, int n4x, int n4w) {
  int i = blockIdx.x * blockDim.x + threadIdx.x;
  const float* src; u16* dst; int j;
  if (i < n4x)            { src = x;  dst = ox;  j = i; }
  else if (i < n4x + n4w) { src = wq; dst = owq; j = i - n4x; }
  else                    { src = wo; dst = owo; j = i - n4x - n4w;
                            if (j >= n4w) return; }
  float4 v = ((const float4*)src)[j];
  ushort4 o;
  o.x = f2bf(v.x); o.y = f2bf(v.y); o.z = f2bf(v.z); o.w = f2bf(v.w);
  ((ushort4*)dst)[j] = o;
}

// C = act(A @ Bt^T + bias) * oscale. 128x64 tile, BK=64, 4 waves (2x2).
// 2-phase pipeline: double-buffered LDS, stage(next) before compute(cur),
// ONE barrier per K-step. No XCD swizzle (L3-fit inputs: swizzle hurts).
template <bool GELU, typename OT>
__global__ __launch_bounds__(256)
void gemm_bt(const u16* __restrict__ A, const u16* __restrict__ Bt,
             const float* __restrict__ bias, OT* __restrict__ C,
             int M, int N, int K, float oscale) {
  __shared__ u16 As[2][128 * 64];
  __shared__ u16 Bs[2][64 * 64];
  const int lane = threadIdx.x & 63, wave = threadIdx.x >> 6;
  const int ln = lane & 15, g = lane >> 4;
  const int m0 = blockIdx.y * 128, n0 = blockIdx.x * 64;
  const int wm = wave >> 1, wn = wave & 1;
  f32x4 acc[4][2] = {};

  auto stage = [&](int buf, int k0) {
#pragma unroll
    for (int rd = 0; rd < 6; ++rd) {
      int ch = rd * 4 + wave;                   // 0..23: 16 A-chunks + 8 B-chunks
      if (ch < 16) {
        int flatb = ch * 1024 + lane * 16;
        int row = flatb >> 7;
        int within = (flatb & 127) ^ ((row & 7) << 4);
        g2l16((const char*)A + ((size_t)(m0 + row) * K + k0) * 2 + within,
              (char*)As[buf] + ch * 1024);
      } else {
        int flatb = (ch - 16) * 1024 + lane * 16;
        int row = flatb >> 7;
        int within = (flatb & 127) ^ ((row & 7) << 4);
        g2l16((const char*)Bt + ((size_t)(n0 + row) * K + k0) * 2 + within,
              (char*)Bs[buf] + (ch - 16) * 1024);
      }
    }
  };

  stage(0, 0);
  __syncthreads();
  const int NT = K / 64;
  for (int t = 0; t < NT; ++t) {
    const int cur = t & 1;
    if (t + 1 < NT) stage(cur ^ 1, (t + 1) * 64);
#pragma unroll
    for (int kc = 0; kc < 2; ++kc) {
      bf16x8 af[4], bfr[2];
#pragma unroll
      for (int i = 0; i < 4; ++i) {
        int ra = wm * 64 + i * 16 + ln;
        af[i] = *(const bf16x8*)((const char*)As[cur] + ra * 128 +
                                 ((kc * 64 + g * 16) ^ ((ra & 7) << 4)));
      }
#pragma unroll
      for (int j = 0; j < 2; ++j) {
        int rb = wn * 32 + j * 16 + ln;
        bfr[j] = *(const bf16x8*)((const char*)Bs[cur] + rb * 128 +
                                  ((kc * 64 + g * 16) ^ ((rb & 7) << 4)));
      }
#pragma unroll
      for (int i = 0; i < 4; ++i)
#pragma unroll
        for (int j = 0; j < 2; ++j)
          acc[i][j] = __builtin_amdgcn_mfma_f32_16x16x32_bf16(af[i], bfr[j], acc[i][j], 0, 0, 0);
    }
    __syncthreads();   // drains this iter's prefetch + fences buffer reuse
  }

#pragma unroll
  for (int j = 0; j < 2; ++j) {
    int gc = n0 + wn * 32 + j * 16 + ln;
    float bv = bias[gc];
#pragma unroll
    for (int i = 0; i < 4; ++i) {
      int gr0 = m0 + wm * 64 + i * 16 + g * 4;
#pragma unroll
      for (int r = 0; r < 4; ++r) {
        float v = acc[i][j][r] + bv;
        if constexpr (GELU) v = gelu_fast(v);
        v *= oscale;
        if constexpr (sizeof(OT) == 2) C[(size_t)(gr0 + r) * N + gc] = (OT)f2bf(v);
        else                           C[(size_t)(gr0 + r) * N + gc] = (OT)v;
      }
    }
  }
}

// Flash self-attention, token part, K-chunked. QBLK=64 (4 waves x 16 q-rows).
// Swapped QK^T (D[key][q], q=ln lane-local); precomputed LDS offsets;
// compile-time buffer parity (Tag unroll-2). Balanced equal-length key chunks
// + longest-first dispatch. grid (PARTS_PER_BH, H, B).
__global__ __launch_bounds__(256, 4)
void attn(const u16* __restrict__ Q, const u16* __restrict__ Xb,
          u16* __restrict__ CTXP, float* __restrict__ MP, float* __restrict__ LP) {
  // layout: Ks0 @0, Ks1 @8192, Vt0 @16384, Vt1 @24576, Pw @32768 + wave*2048
  __shared__ __attribute__((aligned(16))) char lds[40960];

  const int lane = threadIdx.x & 63, wave = threadIdx.x >> 6;
  const int ln = lane & 15, g = lane >> 4;
  const int h = blockIdx.y, b = blockIdx.z;

  // longest-first: blockIdx 0 -> logical part 79 (qt=31), runts last
  const int pl = PARTS_PER_BH - 1 - blockIdx.x;
  int qt, chunk;
  if (pl < 8)       { qt = pl;                           chunk = 0; }
  else if (pl < 24) { int i = pl - 8;  qt = 8 + (i >> 1);  chunk = i & 1; }
  else if (pl < 48) { int i = pl - 24; qt = 16 + i / 3;    chunk = i % 3; }
  else              { int i = pl - 48; qt = 24 + (i >> 2); chunk = i & 3; }
  // balanced chunk bounds: lengths differ by <=1 (no 1-iter runts)
  const int len = qt + 1;
  const int parts = (len + 7) >> 3;
  const int kt0 = (chunk * len) / parts;
  const int kt1e = ((chunk + 1) * len) / parts;

  const size_t qrow = (size_t)b * S_LEN + qt * 64 + wave * 16 + ln;
  const bf16x8 qa0 = *(const bf16x8*)(Q + qrow * DIM + h * 64 + g * 8);
  const bf16x8 qa1 = *(const bf16x8*)(Q + qrow * DIM + h * 64 + 32 + g * 8);

  // ---- per-lane loop-invariant LDS byte offsets ----
  const int tid = threadIdx.x;
  const int vr0 = (tid >> 3) * 2;   // key row pair (V staging)
  const int vc0 = (tid & 7) * 8;    // dim cols     (V staging)
  const int t7 = tid & 7;
  const int sw7 = (ln & 7) << 4;
  const int kbase0 = ln * 128 + ((g * 16) ^ sw7);        // +cur*8192+sub*2048
  const int kbase1 = ln * 128 + ((64 + g * 16) ^ sw7);
  const int swb = (ln & 7) ^ (ln >> 3);
  int vrd0[4], vrd1[4];                                   // V reads (dim row ns*16+ln)
#pragma unroll
  for (int ns = 0; ns < 4; ++ns) {
    int sw = (swb ^ (ns * 2)) << 4;
    vrd0[ns] = ln * 128 + ((g * 16) ^ sw);
    vrd1[ns] = ln * 128 + ((64 + g * 16) ^ sw);
  }
  int vwr[8];                                             // V^T staging writes
#pragma unroll
  for (int j = 0; j < 8; ++j)
    vwr[j] = (vc0 + j) * 128 + ((vr0 * 2) ^ ((j ^ t7) << 4));
  int pst[4];                                             // P stores
#pragma unroll
  for (int sub = 0; sub < 4; ++sub)
    pst[sub] = 32768 + wave * 2048 + ln * 128 + ((sub * 32 + g * 8) ^ sw7);
  const int prd0 = 32768 + wave * 2048 + ln * 128 + ((g * 16) ^ sw7);
  const int prd1 = 32768 + wave * 2048 + ln * 128 + ((64 + g * 16) ^ sw7);
  int ksrc[2];                                            // K staging src voffsets
#pragma unroll
  for (int rd = 0; rd < 2; ++rd) {
    int ch = rd * 4 + wave;
    int flat = ch * 1024 + lane * 16;
    int row = flat >> 7;
    ksrc[rd] = row * (DIM * 2) + ((flat & 127) ^ ((row & 7) << 4));
  }

  // advancing global byte pointers (uniform stride per key-tile)
  const size_t STEP = (size_t)64 * DIM * 2;
  const char* kq = (const char*)(Q + ((size_t)b * S_LEN + (size_t)kt0 * 64) * DIM + h * 64);
  const char* xv = (const char*)(Xb + ((size_t)b * S_LEN + (size_t)kt0 * 64 + vr0) * DIM + h * 64 + vc0);

  f32x4 acc[4] = {};
  float m_run = -INFINITY;   // per-lane: q = ln (replicated across g)
  float l_run = 0.f;

  // prologue: stage tile kt0 into buffer 0
  {
    bf16x8 r0 = *(const bf16x8*)xv;
    bf16x8 r1 = *(const bf16x8*)(xv + DIM * 2);
#pragma unroll
    for (int rd = 0; rd < 2; ++rd)
      g2l16(kq + ksrc[rd], lds + (rd * 4 + wave) * 1024);
#pragma unroll
    for (int j = 0; j < 8; ++j) {
      unsigned int pack = (unsigned int)(u16)r0[j] | ((unsigned int)(u16)r1[j] << 16);
      *(unsigned int*)(lds + 16384 + vwr[j]) = pack;
    }
  }
  __syncthreads();

  int kt = kt0;
  auto body = [&](auto tag) {
    constexpr int CUR = decltype(tag)::cur;
    constexpr int NXT = CUR ^ 1;
    const bool more = (kt + 1 < kt1e);
    bf16x8 nr0, nr1;
    if (more) {
      const char* nxv = xv + STEP;
      nr0 = *(const bf16x8*)nxv;
      nr1 = *(const bf16x8*)(nxv + DIM * 2);
      const char* nkq = kq + STEP;
#pragma unroll
      for (int rd = 0; rd < 2; ++rd)
        g2l16(nkq + ksrc[rd], lds + NXT * 8192 + (rd * 4 + wave) * 1024);
      __builtin_amdgcn_sched_barrier(0);
    }

    // QK^T SWAPPED: D[key][q]; lane holds key = sub*16 + g*4 + r, q = ln
    float pv_[4][4];
    __builtin_amdgcn_s_setprio(1);
#pragma unroll
    for (int sub = 0; sub < 4; ++sub) {
      bf16x8 kb0 = *(const bf16x8*)(lds + CUR * 8192 + sub * 2048 + kbase0);
      bf16x8 kb1 = *(const bf16x8*)(lds + CUR * 8192 + sub * 2048 + kbase1);
      f32x4 c = {};
      c = __builtin_amdgcn_mfma_f32_16x16x32_bf16(kb0, qa0, c, 0, 0, 0);
      c = __builtin_amdgcn_mfma_f32_16x16x32_bf16(kb1, qa1, c, 0, 0, 0);
      if (kt == qt) {
#pragma unroll
        for (int r = 0; r < 4; ++r) {
          int key = sub * 16 + g * 4 + r;
          pv_[sub][r] = (key > wave * 16 + ln) ? -INFINITY : c[r];
        }
      } else {
#pragma unroll
        for (int r = 0; r < 4; ++r) pv_[sub][r] = c[r];
      }
    }
    __builtin_amdgcn_s_setprio(0);

    // in-lane row max over this lane's 16 scores, then cross-g butterfly
    float pmax = pv_[0][0];
#pragma unroll
    for (int sub = 0; sub < 4; ++sub)
#pragma unroll
      for (int r = 0; r < 4; ++r) pmax = fmaxf(pmax, pv_[sub][r]);
    pmax = fmaxf(pmax, __shfl_xor(pmax, 16));
    pmax = fmaxf(pmax, __shfl_xor(pmax, 32));

    // defer-rescale (THR=8, log2 domain)
    if (!__all(pmax <= m_run + 8.0f)) {
      float m_new = fmaxf(m_run, pmax);
      float scl = exp2f(m_run - m_new);
      m_run = m_new;
      l_run *= scl;
#pragma unroll
      for (int r = 0; r < 4; ++r) {
        float s = __shfl(scl, g * 4 + r);
#pragma unroll
        for (int ns = 0; ns < 4; ++ns) acc[ns][r] *= s;
      }
    }

    float lsum = 0.f;
#pragma unroll
    for (int sub = 0; sub < 4; ++sub)
#pragma unroll
      for (int r = 0; r < 4; ++r) {
        pv_[sub][r] = exp2f(pv_[sub][r] - m_run);
        lsum += pv_[sub][r];
      }
    lsum += __shfl_xor(lsum, 16);
    lsum += __shfl_xor(lsum, 32);
    l_run += lsum;

    // P store: 4 key-consecutive bf16 per (lane,sub) -> one b64 each
#pragma unroll
    for (int sub = 0; sub < 4; ++sub) {
      uint2 val;
      val.x = (unsigned int)f2bfq(pv_[sub][0]) | ((unsigned int)f2bfq(pv_[sub][1]) << 16);
      val.y = (unsigned int)f2bfq(pv_[sub][2]) | ((unsigned int)f2bfq(pv_[sub][3]) << 16);
      *(uint2*)(lds + pst[sub]) = val;
    }

    bf16x8 pa0 = *(const bf16x8*)(lds + prd0);
    bf16x8 pa1 = *(const bf16x8*)(lds + prd1);
    __builtin_amdgcn_s_setprio(1);
#pragma unroll
    for (int ns = 0; ns < 4; ++ns) {
      bf16x8 vb0 = *(const bf16x8*)(lds + 16384 + CUR * 8192 + ns * 2048 + vrd0[ns]);
      bf16x8 vb1 = *(const bf16x8*)(lds + 16384 + CUR * 8192 + ns * 2048 + vrd1[ns]);
      acc[ns] = __builtin_amdgcn_mfma_f32_16x16x32_bf16(pa0, vb0, acc[ns], 0, 0, 0);
      acc[ns] = __builtin_amdgcn_mfma_f32_16x16x32_bf16(pa1, vb1, acc[ns], 0, 0, 0);
    }
    __builtin_amdgcn_s_setprio(0);

    if (more) {
#pragma unroll
      for (int j = 0; j < 8; ++j) {
        unsigned int pack = (unsigned int)(u16)nr0[j] | ((unsigned int)(u16)nr1[j] << 16);
        *(unsigned int*)(lds + 16384 + NXT * 8192 + vwr[j]) = pack;
      }
    }
    __syncthreads();
    kq += STEP; xv += STEP;
  };

  for (;;) {
    body(Tag<0>{});
    if (++kt >= kt1e) break;
    body(Tag<1>{});
    if (++kt >= kt1e) break;
  }

  // write unnormalized bf16 partial ctx + stats (log2-domain m, l)
  const size_t slot = ((size_t)(b * NH + h)) * PARTS_PER_BH + pl;
#pragma unroll
  for (int ns = 0; ns < 4; ++ns)
#pragma unroll
    for (int r = 0; r < 4; ++r) {
      int qr = wave * 16 + g * 4 + r;
      CTXP[slot * 4096 + (size_t)qr * 64 + ns * 16 + ln] = f2bfq(acc[ns][r]);
    }
  if (lane < 16) {
    MP[slot * 64 + wave * 16 + lane] = m_run;
    LP[slot * 64 + wave * 16 + lane] = l_run;
  }
}

// Merge K-chunk partials + fold L=4 memory slots (log2 domain), final bf16 ctx.
// 16 lanes per row (4 rows/wave), lane owns dims ln*4..ln*4+3: all loads
// vectorized (ushort4/float4), slot dots via DPP rsum16 (group-wide result).
__global__ __launch_bounds__(256)
void finalize(const u16* __restrict__ Q, const float* __restrict__ PQ,
              const float* __restrict__ PV, const u16* __restrict__ CTXP,
              const float* __restrict__ MP, const float* __restrict__ LP,
              u16* __restrict__ Cout) {
  const int lane = threadIdx.x & 63, wave = threadIdx.x >> 6;
  const int ln = lane & 15, g = lane >> 4;      // g = row-in-wave
  const size_t row = (size_t)blockIdx.x * 16 + wave * 4 + g;  // (b*H+h)*S + s
  const int s = (int)(row & (S_LEN - 1));
  const int h = (int)((row >> 11) & (NH - 1));
  const int b = (int)(row >> 15);

  const int qt = s >> 6, G = qt >> 3, parts = G + 1;
  const int baseG[4] = {0, 8, 24, 48};
  const int p0 = baseG[G] + (qt & 7) * parts;
  const size_t slot0 = ((size_t)(b * NH + h)) * PARTS_PER_BH + p0;
  const int sr = s & 63;

  // vectorized q segment (4 dims per lane)
  const size_t qoff = ((size_t)b * S_LEN + s) * DIM + h * 64 + ln * 4;
  ushort4 qu = *(const ushort4*)(Q + qoff);
  const float q0 = bf2f(qu.x), q1 = bf2f(qu.y), q2 = bf2f(qu.z), q3 = bf2f(qu.w);

  // memory-slot dots (group-parallel over dims, DPP-reduced)
  const float* pq = PQ + row * (NL * 64);
  const float* pv = PV + row * (NL * 64);
  float msc[NL];
#pragma unroll
  for (int lm = 0; lm < NL; ++lm) {
    float4 v = *(const float4*)(pq + lm * 64 + ln * 4);
    float prod = q0 * v.x + q1 * v.y + q2 * v.z + q3 * v.w;
    msc[lm] = rsum16(prod) * ALPHA;
  }

  // merge token partials (vectorized CTXP reads)
  float mc[4], lc[4];
  float m_tok = -INFINITY;
#pragma unroll
  for (int c = 0; c < 4; ++c)
    if (c < parts) {
      mc[c] = MP[(slot0 + c) * 64 + sr];
      lc[c] = LP[(slot0 + c) * 64 + sr];
      m_tok = fmaxf(m_tok, mc[c]);
    }
  float l_tok = 0.f;
  float cd0 = 0.f, cd1 = 0.f, cd2 = 0.f, cd3 = 0.f;
#pragma unroll
  for (int c = 0; c < 4; ++c)
    if (c < parts) {
      float w = exp2f(mc[c] - m_tok);
      l_tok += w * lc[c];
      ushort4 cu = *(const ushort4*)(CTXP + (slot0 + c) * 4096 + (size_t)sr * 64 + ln * 4);
      cd0 += w * bf2f(cu.x); cd1 += w * bf2f(cu.y);
      cd2 += w * bf2f(cu.z); cd3 += w * bf2f(cu.w);
    }

  float m_fin = m_tok;
#pragma unroll
  for (int lm = 0; lm < NL; ++lm) m_fin = fmaxf(m_fin, msc[lm]);
  const float a = exp2f(m_tok - m_fin);
  float l_fin = l_tok * a;
  cd0 *= a; cd1 *= a; cd2 *= a; cd3 *= a;
#pragma unroll
  for (int lm = 0; lm < NL; ++lm) {
    float w = exp2f(msc[lm] - m_fin);
    l_fin += w;
    float4 v = *(const float4*)(pv + lm * 64 + ln * 4);
    cd0 += w * v.x; cd1 += w * v.y; cd2 += w * v.z; cd3 += w * v.w;
  }
  const float inv = 1.0f / l_fin;
  ushort4 o;
  o.x = f2bfq(cd0 * inv); o.y = f2bfq(cd1 * inv);
  o.z = f2bfq(cd2 * inv); o.w = f2bfq(cd3 * inv);
  *(ushort4*)(Cout + qoff) = o;
}

extern "C" void kernel_launch(void* const* d_in, const int* in_sizes, int n_in,
                              void* d_out, int out_size, void* d_ws, size_t ws_size,
                              hipStream_t stream) {
  const float* x  = (const float*)d_in[0];
  const float* pq = (const float*)d_in[1];
  const float* pv = (const float*)d_in[2];
  const float* Wq = (const float*)d_in[3];
  const float* bq = (const float*)d_in[4];
  const float* Wo = (const float*)d_in[5];
  const float* bo = (const float*)d_in[6];
  float* out = (float*)d_out;

  const int M = NB * S_LEN;  // 4096
  u16*   Qws  = (u16*)d_ws;                    // 8 MB (ALPHA-scaled Q, bf16)
  u16*   Cws  = Qws + (size_t)M * DIM;         // 8 MB
  u16*   xbf  = Cws + (size_t)M * DIM;         // 8 MB
  u16*   Wqbf = xbf + (size_t)M * DIM;         // 2 MB
  u16*   Wobf = Wqbf + (size_t)DIM * DIM;      // 2 MB
  u16*   CTXP = Wobf + (size_t)DIM * DIM;      // 2560 slots x 4096 bf16 = 21 MB
  float* MP   = (float*)(CTXP + (size_t)NB * NH * PARTS_PER_BH * 4096);  // 640 KB
  float* LP   = MP + (size_t)NB * NH * PARTS_PER_BH * 64;                // 640 KB

  const int n4x = M * DIM / 4, n4w = DIM * DIM / 4;
  cvt_all<<<(n4x + 2 * n4w + 255) / 256, 256, 0, stream>>>(
      x, Wq, Wo, xbf, Wqbf, Wobf, n4x, n4w);

  gemm_bt<false, u16><<<dim3(DIM / 64, M / 128), 256, 0, stream>>>(
      xbf, Wqbf, bq, Qws, M, DIM, DIM, ALPHA);
  attn<<<dim3(PARTS_PER_BH, NH, NB), 256, 0, stream>>>(Qws, xbf, CTXP, MP, LP);
  finalize<<<NB * NH * S_LEN / 16, 256, 0, stream>>>(Qws, pq, pv, CTXP, MP, LP, Cws);
  gemm_bt<true, float><<<dim3(DIM / 64, M / 128), 256, 0, stream>>>(
      Cws, Wobf, bo, out, M, DIM, DIM, 1.0f);
}

// Round 13
// 116.300 us; speedup vs baseline: 1.5166x; 1.0487x over previous
//
#include <hip/hip_runtime.h>
#include <hip/hip_bf16.h>
#include <math.h>

#define S_LEN 2048
#define DIM   1024
#define NH    16
#define NL    4
#define NB    2
#define PARTS_PER_BH 80   // sum over 32 q-tiles(64) of ceil((qt+1)/8)
#define ALPHA 0.42466086f // sqrt(0.125 * log2(e)); folded into Q

typedef __attribute__((ext_vector_type(8))) short bf16x8;
typedef __attribute__((ext_vector_type(4))) float f32x4;
typedef unsigned short u16;

template <int N> struct Tag { static constexpr int cur = N; };

__device__ __forceinline__ float bf2f(u16 u) {
  union { unsigned int i; float f; } x; x.i = ((unsigned int)u) << 16; return x.f;
}
__device__ __forceinline__ u16 f2bf(float f) {  // RNE, integer path
  union { float f; unsigned int i; } x; x.f = f;
  unsigned int r = x.i + 0x7fffu + ((x.i >> 16) & 1u);
  return (u16)(r >> 16);
}
__device__ __forceinline__ u16 f2bfq(float f) { // compiler cvt path
  __hip_bfloat16 h = __float2bfloat16(f);
  return *reinterpret_cast<u16*>(&h);
}
// raw v_exp_f32: quarter-rate single instr; args here are <=0 / -inf, never NaN
__device__ __forceinline__ float ex2(float x) {
  return __builtin_amdgcn_exp2f(x);
}

__device__ __forceinline__ void g2l16(const void* g, void* l) {
  __builtin_amdgcn_global_load_lds(
      (const __attribute__((address_space(1))) void*)g,
      (__attribute__((address_space(3))) void*)l, 16, 0, 0);
}

// DPP 16-lane butterfly sum (VALU-speed; controls verified in R3-R11).
template <int CTRL>
__device__ __forceinline__ float dppf(float x) {
  union { float f; int i; } u, r;
  u.f = x;
  r.i = __builtin_amdgcn_update_dpp(0, u.i, CTRL, 0xF, 0xF, true);
  return r.f;
}
__device__ __forceinline__ float rsum16(float x) {
  x += dppf<0xB1>(x);
  x += dppf<0x4E>(x);
  x += dppf<0x141>(x);
  x += dppf<0x140>(x);
  return x;
}

// gelu via tanh form, tanh via one raw exp2. |err vs exact erf-gelu| <= ~3e-4.
__device__ __forceinline__ float gelu_fast(float v) {
  float y = 0.79788456f * (v + 0.044715f * v * v * v);
  float e = ex2(y * 2.88539008f);            // e^(2y)
  float t = 1.0f - 2.0f / (e + 1.0f);        // tanh(y)
  return 0.5f * v * (1.0f + t);
}

// One fused f32->bf16 convert for x, Wq, Wo.
__global__ __launch_bounds__(256)
void cvt_all(const float* __restrict__ x, const float* __restrict__ wq,
             const float* __restrict__ wo, u16* __restrict__ ox,
             u16* __restrict__ owq, u16* __restrict__ owo, int n4x, int n4w) {
  int i = blockIdx.x * blockDim.x + threadIdx.x;
  const float* src; u16* dst; int j;
  if (i < n4x)            { src = x;  dst = ox;  j = i; }
  else if (i < n4x + n4w) { src = wq; dst = owq; j = i - n4x; }
  else                    { src = wo; dst = owo; j = i - n4x - n4w;
                            if (j >= n4w) return; }
  float4 v = ((const float4*)src)[j];
  ushort4 o;
  o.x = f2bf(v.x); o.y = f2bf(v.y); o.z = f2bf(v.z); o.w = f2bf(v.w);
  ((ushort4*)dst)[j] = o;
}

// C = act(A @ Bt^T + bias) * oscale. 128x64 tile, BK=64, 4 waves (2x2).
// 2-phase pipeline: double-buffered LDS, stage(next) before compute(cur),
// ONE barrier per K-step. No XCD swizzle (L3-fit inputs: swizzle hurts).
template <bool GELU, typename OT>
__global__ __launch_bounds__(256)
void gemm_bt(const u16* __restrict__ A, const u16* __restrict__ Bt,
             const float* __restrict__ bias, OT* __restrict__ C,
             int M, int N, int K, float oscale) {
  __shared__ u16 As[2][128 * 64];
  __shared__ u16 Bs[2][64 * 64];
  const int lane = threadIdx.x & 63, wave = threadIdx.x >> 6;
  const int ln = lane & 15, g = lane >> 4;
  const int m0 = blockIdx.y * 128, n0 = blockIdx.x * 64;
  const int wm = wave >> 1, wn = wave & 1;
  f32x4 acc[4][2] = {};

  auto stage = [&](int buf, int k0) {
#pragma unroll
    for (int rd = 0; rd < 6; ++rd) {
      int ch = rd * 4 + wave;                   // 0..23: 16 A-chunks + 8 B-chunks
      if (ch < 16) {
        int flatb = ch * 1024 + lane * 16;
        int row = flatb >> 7;
        int within = (flatb & 127) ^ ((row & 7) << 4);
        g2l16((const char*)A + ((size_t)(m0 + row) * K + k0) * 2 + within,
              (char*)As[buf] + ch * 1024);
      } else {
        int flatb = (ch - 16) * 1024 + lane * 16;
        int row = flatb >> 7;
        int within = (flatb & 127) ^ ((row & 7) << 4);
        g2l16((const char*)Bt + ((size_t)(n0 + row) * K + k0) * 2 + within,
              (char*)Bs[buf] + (ch - 16) * 1024);
      }
    }
  };

  stage(0, 0);
  __syncthreads();
  const int NT = K / 64;
  for (int t = 0; t < NT; ++t) {
    const int cur = t & 1;
    if (t + 1 < NT) stage(cur ^ 1, (t + 1) * 64);
#pragma unroll
    for (int kc = 0; kc < 2; ++kc) {
      bf16x8 af[4], bfr[2];
#pragma unroll
      for (int i = 0; i < 4; ++i) {
        int ra = wm * 64 + i * 16 + ln;
        af[i] = *(const bf16x8*)((const char*)As[cur] + ra * 128 +
                                 ((kc * 64 + g * 16) ^ ((ra & 7) << 4)));
      }
#pragma unroll
      for (int j = 0; j < 2; ++j) {
        int rb = wn * 32 + j * 16 + ln;
        bfr[j] = *(const bf16x8*)((const char*)Bs[cur] + rb * 128 +
                                  ((kc * 64 + g * 16) ^ ((rb & 7) << 4)));
      }
#pragma unroll
      for (int i = 0; i < 4; ++i)
#pragma unroll
        for (int j = 0; j < 2; ++j)
          acc[i][j] = __builtin_amdgcn_mfma_f32_16x16x32_bf16(af[i], bfr[j], acc[i][j], 0, 0, 0);
    }
    __syncthreads();   // drains this iter's prefetch + fences buffer reuse
  }

#pragma unroll
  for (int j = 0; j < 2; ++j) {
    int gc = n0 + wn * 32 + j * 16 + ln;
    float bv = bias[gc];
#pragma unroll
    for (int i = 0; i < 4; ++i) {
      int gr0 = m0 + wm * 64 + i * 16 + g * 4;
#pragma unroll
      for (int r = 0; r < 4; ++r) {
        float v = acc[i][j][r] + bv;
        if constexpr (GELU) v = gelu_fast(v);
        v *= oscale;
        if constexpr (sizeof(OT) == 2) C[(size_t)(gr0 + r) * N + gc] = (OT)f2bf(v);
        else                           C[(size_t)(gr0 + r) * N + gc] = (OT)v;
      }
    }
  }
}

// Flash self-attention, token part, K-chunked. QBLK=64 (4 waves x 16 q-rows).
// Swapped QK^T (D[key][q], q=ln lane-local); precomputed LDS offsets;
// compile-time buffer parity (Tag unroll-2); raw v_exp_f32 softmax.
// Balanced equal-length key chunks + longest-first dispatch.
__global__ __launch_bounds__(256, 4)
void attn(const u16* __restrict__ Q, const u16* __restrict__ Xb,
          u16* __restrict__ CTXP, float* __restrict__ MP, float* __restrict__ LP) {
  // layout: Ks0 @0, Ks1 @8192, Vt0 @16384, Vt1 @24576, Pw @32768 + wave*2048
  __shared__ __attribute__((aligned(16))) char lds[40960];

  const int lane = threadIdx.x & 63, wave = threadIdx.x >> 6;
  const int ln = lane & 15, g = lane >> 4;
  const int h = blockIdx.y, b = blockIdx.z;

  // longest-first: blockIdx 0 -> logical part 79 (qt=31), runts last
  const int pl = PARTS_PER_BH - 1 - blockIdx.x;
  int qt, chunk;
  if (pl < 8)       { qt = pl;                           chunk = 0; }
  else if (pl < 24) { int i = pl - 8;  qt = 8 + (i >> 1);  chunk = i & 1; }
  else if (pl < 48) { int i = pl - 24; qt = 16 + i / 3;    chunk = i % 3; }
  else              { int i = pl - 48; qt = 24 + (i >> 2); chunk = i & 3; }
  // balanced chunk bounds: lengths differ by <=1 (no 1-iter runts)
  const int len = qt + 1;
  const int parts = (len + 7) >> 3;
  const int kt0 = (chunk * len) / parts;
  const int kt1e = ((chunk + 1) * len) / parts;

  const size_t qrow = (size_t)b * S_LEN + qt * 64 + wave * 16 + ln;
  const bf16x8 qa0 = *(const bf16x8*)(Q + qrow * DIM + h * 64 + g * 8);
  const bf16x8 qa1 = *(const bf16x8*)(Q + qrow * DIM + h * 64 + 32 + g * 8);

  // ---- per-lane loop-invariant LDS byte offsets ----
  const int tid = threadIdx.x;
  const int vr0 = (tid >> 3) * 2;   // key row pair (V staging)
  const int vc0 = (tid & 7) * 8;    // dim cols     (V staging)
  const int t7 = tid & 7;
  const int sw7 = (ln & 7) << 4;
  const int kbase0 = ln * 128 + ((g * 16) ^ sw7);        // +cur*8192+sub*2048
  const int kbase1 = ln * 128 + ((64 + g * 16) ^ sw7);
  const int swb = (ln & 7) ^ (ln >> 3);
  int vrd0[4], vrd1[4];                                   // V reads (dim row ns*16+ln)
#pragma unroll
  for (int ns = 0; ns < 4; ++ns) {
    int sw = (swb ^ (ns * 2)) << 4;
    vrd0[ns] = ln * 128 + ((g * 16) ^ sw);
    vrd1[ns] = ln * 128 + ((64 + g * 16) ^ sw);
  }
  int vwr[8];                                             // V^T staging writes
#pragma unroll
  for (int j = 0; j < 8; ++j)
    vwr[j] = (vc0 + j) * 128 + ((vr0 * 2) ^ ((j ^ t7) << 4));
  int pst[4];                                             // P stores
#pragma unroll
  for (int sub = 0; sub < 4; ++sub)
    pst[sub] = 32768 + wave * 2048 + ln * 128 + ((sub * 32 + g * 8) ^ sw7);
  const int prd0 = 32768 + wave * 2048 + ln * 128 + ((g * 16) ^ sw7);
  const int prd1 = 32768 + wave * 2048 + ln * 128 + ((64 + g * 16) ^ sw7);
  int ksrc[2];                                            // K staging src voffsets
#pragma unroll
  for (int rd = 0; rd < 2; ++rd) {
    int ch = rd * 4 + wave;
    int flat = ch * 1024 + lane * 16;
    int row = flat >> 7;
    ksrc[rd] = row * (DIM * 2) + ((flat & 127) ^ ((row & 7) << 4));
  }

  // advancing global byte pointers (uniform stride per key-tile)
  const size_t STEP = (size_t)64 * DIM * 2;
  const char* kq = (const char*)(Q + ((size_t)b * S_LEN + (size_t)kt0 * 64) * DIM + h * 64);
  const char* xv = (const char*)(Xb + ((size_t)b * S_LEN + (size_t)kt0 * 64 + vr0) * DIM + h * 64 + vc0);

  f32x4 acc[4] = {};
  float m_run = -INFINITY;   // per-lane: q = ln (replicated across g)
  float l_run = 0.f;

  // prologue: stage tile kt0 into buffer 0
  {
    bf16x8 r0 = *(const bf16x8*)xv;
    bf16x8 r1 = *(const bf16x8*)(xv + DIM * 2);
#pragma unroll
    for (int rd = 0; rd < 2; ++rd)
      g2l16(kq + ksrc[rd], lds + (rd * 4 + wave) * 1024);
#pragma unroll
    for (int j = 0; j < 8; ++j) {
      unsigned int pack = (unsigned int)(u16)r0[j] | ((unsigned int)(u16)r1[j] << 16);
      *(unsigned int*)(lds + 16384 + vwr[j]) = pack;
    }
  }
  __syncthreads();

  int kt = kt0;
  auto body = [&](auto tag) {
    constexpr int CUR = decltype(tag)::cur;
    constexpr int NXT = CUR ^ 1;
    const bool more = (kt + 1 < kt1e);
    bf16x8 nr0, nr1;
    if (more) {
      const char* nxv = xv + STEP;
      nr0 = *(const bf16x8*)nxv;
      nr1 = *(const bf16x8*)(nxv + DIM * 2);
      const char* nkq = kq + STEP;
#pragma unroll
      for (int rd = 0; rd < 2; ++rd)
        g2l16(nkq + ksrc[rd], lds + NXT * 8192 + (rd * 4 + wave) * 1024);
      __builtin_amdgcn_sched_barrier(0);
    }

    // QK^T SWAPPED: D[key][q]; lane holds key = sub*16 + g*4 + r, q = ln
    float pv_[4][4];
    __builtin_amdgcn_s_setprio(1);
#pragma unroll
    for (int sub = 0; sub < 4; ++sub) {
      bf16x8 kb0 = *(const bf16x8*)(lds + CUR * 8192 + sub * 2048 + kbase0);
      bf16x8 kb1 = *(const bf16x8*)(lds + CUR * 8192 + sub * 2048 + kbase1);
      f32x4 c = {};
      c = __builtin_amdgcn_mfma_f32_16x16x32_bf16(kb0, qa0, c, 0, 0, 0);
      c = __builtin_amdgcn_mfma_f32_16x16x32_bf16(kb1, qa1, c, 0, 0, 0);
      if (kt == qt) {
#pragma unroll
        for (int r = 0; r < 4; ++r) {
          int key = sub * 16 + g * 4 + r;
          pv_[sub][r] = (key > wave * 16 + ln) ? -INFINITY : c[r];
        }
      } else {
#pragma unroll
        for (int r = 0; r < 4; ++r) pv_[sub][r] = c[r];
      }
    }
    __builtin_amdgcn_s_setprio(0);

    // in-lane row max over this lane's 16 scores, then cross-g butterfly
    float pmax = pv_[0][0];
#pragma unroll
    for (int sub = 0; sub < 4; ++sub)
#pragma unroll
      for (int r = 0; r < 4; ++r) pmax = fmaxf(pmax, pv_[sub][r]);
    pmax = fmaxf(pmax, __shfl_xor(pmax, 16));
    pmax = fmaxf(pmax, __shfl_xor(pmax, 32));

    // defer-rescale (THR=8, log2 domain)
    if (!__all(pmax <= m_run + 8.0f)) {
      float m_new = fmaxf(m_run, pmax);
      float scl = ex2(m_run - m_new);
      m_run = m_new;
      l_run *= scl;
#pragma unroll
      for (int r = 0; r < 4; ++r) {
        float s = __shfl(scl, g * 4 + r);
#pragma unroll
        for (int ns = 0; ns < 4; ++ns) acc[ns][r] *= s;
      }
    }

    float lsum = 0.f;
#pragma unroll
    for (int sub = 0; sub < 4; ++sub)
#pragma unroll
      for (int r = 0; r < 4; ++r) {
        pv_[sub][r] = ex2(pv_[sub][r] - m_run);
        lsum += pv_[sub][r];
      }
    lsum += __shfl_xor(lsum, 16);
    lsum += __shfl_xor(lsum, 32);
    l_run += lsum;

    // P store: 4 key-consecutive bf16 per (lane,sub) -> one b64 each
#pragma unroll
    for (int sub = 0; sub < 4; ++sub) {
      uint2 val;
      val.x = (unsigned int)f2bfq(pv_[sub][0]) | ((unsigned int)f2bfq(pv_[sub][1]) << 16);
      val.y = (unsigned int)f2bfq(pv_[sub][2]) | ((unsigned int)f2bfq(pv_[sub][3]) << 16);
      *(uint2*)(lds + pst[sub]) = val;
    }

    bf16x8 pa0 = *(const bf16x8*)(lds + prd0);
    bf16x8 pa1 = *(const bf16x8*)(lds + prd1);
    __builtin_amdgcn_s_setprio(1);
#pragma unroll
    for (int ns = 0; ns < 4; ++ns) {
      bf16x8 vb0 = *(const bf16x8*)(lds + 16384 + CUR * 8192 + ns * 2048 + vrd0[ns]);
      bf16x8 vb1 = *(const bf16x8*)(lds + 16384 + CUR * 8192 + ns * 2048 + vrd1[ns]);
      acc[ns] = __builtin_amdgcn_mfma_f32_16x16x32_bf16(pa0, vb0, acc[ns], 0, 0, 0);
      acc[ns] = __builtin_amdgcn_mfma_f32_16x16x32_bf16(pa1, vb1, acc[ns], 0, 0, 0);
    }
    __builtin_amdgcn_s_setprio(0);

    if (more) {
#pragma unroll
      for (int j = 0; j < 8; ++j) {
        unsigned int pack = (unsigned int)(u16)nr0[j] | ((unsigned int)(u16)nr1[j] << 16);
        *(unsigned int*)(lds + 16384 + NXT * 8192 + vwr[j]) = pack;
      }
    }
    __syncthreads();
    kq += STEP; xv += STEP;
  };

  for (;;) {
    body(Tag<0>{});
    if (++kt >= kt1e) break;
    body(Tag<1>{});
    if (++kt >= kt1e) break;
  }

  // write unnormalized bf16 partial ctx + stats (log2-domain m, l)
  const size_t slot = ((size_t)(b * NH + h)) * PARTS_PER_BH + pl;
#pragma unroll
  for (int ns = 0; ns < 4; ++ns)
#pragma unroll
    for (int r = 0; r < 4; ++r) {
      int qr = wave * 16 + g * 4 + r;
      CTXP[slot * 4096 + (size_t)qr * 64 + ns * 16 + ln] = f2bfq(acc[ns][r]);
    }
  if (lane < 16) {
    MP[slot * 64 + wave * 16 + lane] = m_run;
    LP[slot * 64 + wave * 16 + lane] = l_run;
  }
}

// Merge K-chunk partials + fold L=4 memory slots (log2 domain), final bf16 ctx.
// 16 lanes per row (4 rows/wave), lane owns dims ln*4..ln*4+3: all loads
// vectorized (ushort4/float4), slot dots via DPP rsum16 (group-wide result).
__global__ __launch_bounds__(256)
void finalize(const u16* __restrict__ Q, const float* __restrict__ PQ,
              const float* __restrict__ PV, const u16* __restrict__ CTXP,
              const float* __restrict__ MP, const float* __restrict__ LP,
              u16* __restrict__ Cout) {
  const int lane = threadIdx.x & 63, wave = threadIdx.x >> 6;
  const int ln = lane & 15, g = lane >> 4;      // g = row-in-wave
  const size_t row = (size_t)blockIdx.x * 16 + wave * 4 + g;  // (b*H+h)*S + s
  const int s = (int)(row & (S_LEN - 1));
  const int h = (int)((row >> 11) & (NH - 1));
  const int b = (int)(row >> 15);

  const int qt = s >> 6, G = qt >> 3, parts = G + 1;
  const int baseG[4] = {0, 8, 24, 48};
  const int p0 = baseG[G] + (qt & 7) * parts;
  const size_t slot0 = ((size_t)(b * NH + h)) * PARTS_PER_BH + p0;
  const int sr = s & 63;

  // vectorized q segment (4 dims per lane)
  const size_t qoff = ((size_t)b * S_LEN + s) * DIM + h * 64 + ln * 4;
  ushort4 qu = *(const ushort4*)(Q + qoff);
  const float q0 = bf2f(qu.x), q1 = bf2f(qu.y), q2 = bf2f(qu.z), q3 = bf2f(qu.w);

  // memory-slot dots (group-parallel over dims, DPP-reduced)
  const float* pq = PQ + row * (NL * 64);
  const float* pv = PV + row * (NL * 64);
  float msc[NL];
#pragma unroll
  for (int lm = 0; lm < NL; ++lm) {
    float4 v = *(const float4*)(pq + lm * 64 + ln * 4);
    float prod = q0 * v.x + q1 * v.y + q2 * v.z + q3 * v.w;
    msc[lm] = rsum16(prod) * ALPHA;
  }

  // merge token partials (vectorized CTXP reads)
  float mc[4], lc[4];
  float m_tok = -INFINITY;
#pragma unroll
  for (int c = 0; c < 4; ++c)
    if (c < parts) {
      mc[c] = MP[(slot0 + c) * 64 + sr];
      lc[c] = LP[(slot0 + c) * 64 + sr];
      m_tok = fmaxf(m_tok, mc[c]);
    }
  float l_tok = 0.f;
  float cd0 = 0.f, cd1 = 0.f, cd2 = 0.f, cd3 = 0.f;
#pragma unroll
  for (int c = 0; c < 4; ++c)
    if (c < parts) {
      float w = ex2(mc[c] - m_tok);
      l_tok += w * lc[c];
      ushort4 cu = *(const ushort4*)(CTXP + (slot0 + c) * 4096 + (size_t)sr * 64 + ln * 4);
      cd0 += w * bf2f(cu.x); cd1 += w * bf2f(cu.y);
      cd2 += w * bf2f(cu.z); cd3 += w * bf2f(cu.w);
    }

  float m_fin = m_tok;
#pragma unroll
  for (int lm = 0; lm < NL; ++lm) m_fin = fmaxf(m_fin, msc[lm]);
  const float a = ex2(m_tok - m_fin);
  float l_fin = l_tok * a;
  cd0 *= a; cd1 *= a; cd2 *= a; cd3 *= a;
#pragma unroll
  for (int lm = 0; lm < NL; ++lm) {
    float w = ex2(msc[lm] - m_fin);
    l_fin += w;
    float4 v = *(const float4*)(pv + lm * 64 + ln * 4);
    cd0 += w * v.x; cd1 += w * v.y; cd2 += w * v.z; cd3 += w * v.w;
  }
  const float inv = 1.0f / l_fin;
  ushort4 o;
  o.x = f2bfq(cd0 * inv); o.y = f2bfq(cd1 * inv);
  o.z = f2bfq(cd2 * inv); o.w = f2bfq(cd3 * inv);
  *(ushort4*)(Cout + qoff) = o;
}

extern "C" void kernel_launch(void* const* d_in, const int* in_sizes, int n_in,
                              void* d_out, int out_size, void* d_ws, size_t ws_size,
                              hipStream_t stream) {
  const float* x  = (const float*)d_in[0];
  const float* pq = (const float*)d_in[1];
  const float* pv = (const float*)d_in[2];
  const float* Wq = (const float*)d_in[3];
  const float* bq = (const float*)d_in[4];
  const float* Wo = (const float*)d_in[5];
  const float* bo = (const float*)d_in[6];
  float* out = (float*)d_out;

  const int M = NB * S_LEN;  // 4096
  u16*   Qws  = (u16*)d_ws;                    // 8 MB (ALPHA-scaled Q, bf16)
  u16*   Cws  = Qws + (size_t)M * DIM;         // 8 MB
  u16*   xbf  = Cws + (size_t)M * DIM;         // 8 MB
  u16*   Wqbf = xbf + (size_t)M * DIM;         // 2 MB
  u16*   Wobf = Wqbf + (size_t)DIM * DIM;      // 2 MB
  u16*   CTXP = Wobf + (size_t)DIM * DIM;      // 2560 slots x 4096 bf16 = 21 MB
  float* MP   = (float*)(CTXP + (size_t)NB * NH * PARTS_PER_BH * 4096);  // 640 KB
  float* LP   = MP + (size_t)NB * NH * PARTS_PER_BH * 64;                // 640 KB

  const int n4x = M * DIM / 4, n4w = DIM * DIM / 4;
  cvt_all<<<(n4x + 2 * n4w + 255) / 256, 256, 0, stream>>>(
      x, Wq, Wo, xbf, Wqbf, Wobf, n4x, n4w);

  gemm_bt<false, u16><<<dim3(DIM / 64, M / 128), 256, 0, stream>>>(
      xbf, Wqbf, bq, Qws, M, DIM, DIM, ALPHA);
  attn<<<dim3(PARTS_PER_BH, NH, NB), 256, 0, stream>>>(Qws, xbf, CTXP, MP, LP);
  finalize<<<NB * NH * S_LEN / 16, 256, 0, stream>>>(Qws, pq, pv, CTXP, MP, LP, Cws);
  gemm_bt<true, float><<<dim3(DIM / 64, M / 128), 256, 0, stream>>>(
      Cws, Wobf, bo, out, M, DIM, DIM, 1.0f);
}